// Round 18
// baseline (437.994 us; speedup 1.0000x reference)
//
#include <hip/hip_runtime.h>
#include <hip/hip_bf16.h>
#include <math.h>

#define B_ 4
#define H_ 128
#define W_ 128
#define N_ 16384

using bf16 = __hip_bfloat16;
typedef short short8 __attribute__((ext_vector_type(8)));
typedef short s16x4 __attribute__((ext_vector_type(4)));
typedef float f32x4 __attribute__((ext_vector_type(4)));

__device__ __forceinline__ float toF(float v) { return v; }
__device__ __forceinline__ float toF(bf16 v) { return __bfloat162float(v); }
__device__ __forceinline__ void storeF(float* p, float v) { *p = v; }
__device__ __forceinline__ void storeF(bf16* p, float v) { *p = __float2bfloat16(v); }

__device__ __forceinline__ unsigned short f2bf(float f) {
  unsigned u = __builtin_bit_cast(unsigned, f);
  unsigned r = (u + 0x7FFFu + ((u >> 16) & 1u)) >> 16;
  return (unsigned short)r;
}
__device__ __forceinline__ short rawbf(float v) { return (short)f2bf(v); }
__device__ __forceinline__ short rawbf(bf16 v) { return __builtin_bit_cast(short, v); }
__device__ __forceinline__ float bfs2f(short s) {
  return __builtin_bit_cast(float, ((unsigned)(unsigned short)s) << 16);
}

// load 8 contiguous bf16 as raw shorts
__device__ __forceinline__ short8 ld8(const bf16* p) { return *(const short8*)p; }

// store short8 (8 bf16) into patch row as 2 aligned float4
__device__ __forceinline__ void st8f(float* dst, short8 v) {
  float4 a, b2;
  a.x = bfs2f(v[0]); a.y = bfs2f(v[1]); a.z = bfs2f(v[2]); a.w = bfs2f(v[3]);
  b2.x = bfs2f(v[4]); b2.y = bfs2f(v[5]); b2.z = bfs2f(v[6]); b2.w = bfs2f(v[7]);
  *(float4*)dst = a;
  *(float4*)(dst + 4) = b2;
}

// ===== MFMA GEMM: Y[b][oc][n] = sum_ic W[oc][ic] * X[b][ic][n] (channel-major X) =====
template <typename TX, typename TY>
__global__ __launch_bounds__(256) void gemm_mfma(
    const bf16* __restrict__ Wb, const TX* __restrict__ X, TY* __restrict__ Y, int IC) {
  __shared__ short smA[8192];
  __shared__ short smB[8192];
  int tid = threadIdx.x;
  int lane = tid & 63, w = tid >> 6;
  int wm = w >> 1, wn = w & 1;
  int n0 = blockIdx.x * 128, oc0 = blockIdx.y * 128, b = blockIdx.z;
  const TX* Xb = X + (size_t)b * IC * N_;
  TY* Yb = Y + (size_t)b * (gridDim.y * 128) * N_;
  f32x4 acc[4][4] = {};
  int nB = tid & 127;
  int gB0 = tid >> 7;

  for (int k0 = 0; k0 < IC; k0 += 64) {
    short8 areg[4], breg[4];
#pragma unroll
    for (int i = 0; i < 4; i++) {
      int q = i * 256 + tid;
      int rowA = q >> 3, gA = q & 7;
      areg[i] = ld8(Wb + (size_t)(oc0 + rowA) * IC + k0 + gA * 8);
      int gB = i * 2 + gB0;
      const TX* src = Xb + (size_t)(k0 + gB * 8) * N_ + n0 + nB;
      short8 v;
#pragma unroll
      for (int j = 0; j < 8; j++) v[j] = rawbf(src[(size_t)j * N_]);
      breg[i] = v;
    }
    __syncthreads();
#pragma unroll
    for (int i = 0; i < 4; i++) {
      int q = i * 256 + tid;
      int rowA = q >> 3, gA = q & 7;
      *(short8*)&smA[rowA * 64 + ((gA ^ (rowA & 7)) * 8)] = areg[i];
      int gB = i * 2 + gB0;
      *(short8*)&smB[nB * 64 + ((gB ^ (nB & 7)) * 8)] = breg[i];
    }
    __syncthreads();
#pragma unroll
    for (int ks = 0; ks < 2; ks++) {
      int gk = ks * 4 + (lane >> 4);
      short8 af[4], bfr[4];
#pragma unroll
      for (int mf = 0; mf < 4; mf++) {
        int row = wm * 64 + mf * 16 + (lane & 15);
        af[mf] = *(const short8*)&smA[row * 64 + ((gk ^ (row & 7)) * 8)];
      }
#pragma unroll
      for (int nf = 0; nf < 4; nf++) {
        int nr = wn * 64 + nf * 16 + (lane & 15);
        bfr[nf] = *(const short8*)&smB[nr * 64 + ((gk ^ (nr & 7)) * 8)];
      }
#pragma unroll
      for (int nf = 0; nf < 4; nf++)
#pragma unroll
        for (int mf = 0; mf < 4; mf++)
          acc[mf][nf] = __builtin_amdgcn_mfma_f32_16x16x32_bf16(af[mf], bfr[nf], acc[mf][nf], 0, 0, 0);
    }
    __syncthreads();
  }
#pragma unroll
  for (int mf = 0; mf < 4; mf++)
#pragma unroll
    for (int nf = 0; nf < 4; nf++) {
      int ocr = oc0 + wm * 64 + mf * 16 + ((lane >> 4) << 2);
      int nc = n0 + wn * 64 + nf * 16 + (lane & 15);
#pragma unroll
      for (int j = 0; j < 4; j++)
        storeF(&Yb[(size_t)(ocr + j) * N_ + nc], acc[mf][nf][j]);
    }
}

// ===== gemm_mfmaT: like gemm_mfma but X is n-major (xT[b][n][ic]); vector B staging =====
__global__ __launch_bounds__(256) void gemm_mfmaT(
    const bf16* __restrict__ Wb, const bf16* __restrict__ XT, bf16* __restrict__ Y, int IC) {
  __shared__ short smA[8192];
  __shared__ short smB[8192];
  int tid = threadIdx.x;
  int lane = tid & 63, w = tid >> 6;
  int wm = w >> 1, wn = w & 1;
  int n0 = blockIdx.x * 128, oc0 = blockIdx.y * 128, b = blockIdx.z;
  const bf16* Xb = XT + (size_t)b * N_ * IC;
  bf16* Yb = Y + (size_t)b * (gridDim.y * 128) * N_;
  f32x4 acc[4][4] = {};

  for (int k0 = 0; k0 < IC; k0 += 64) {
    short8 areg[4], breg[4];
#pragma unroll
    for (int i = 0; i < 4; i++) {
      int q = i * 256 + tid;
      int rowA = q >> 3, gA = q & 7;
      areg[i] = ld8(Wb + (size_t)(oc0 + rowA) * IC + k0 + gA * 8);
      breg[i] = ld8(Xb + (size_t)(n0 + rowA) * IC + k0 + gA * 8);
    }
    __syncthreads();
#pragma unroll
    for (int i = 0; i < 4; i++) {
      int q = i * 256 + tid;
      int rowA = q >> 3, gA = q & 7;
      int so = (gA ^ (rowA & 7)) * 8;
      *(short8*)&smA[rowA * 64 + so] = areg[i];
      *(short8*)&smB[rowA * 64 + so] = breg[i];
    }
    __syncthreads();
#pragma unroll
    for (int ks = 0; ks < 2; ks++) {
      int gk = ks * 4 + (lane >> 4);
      short8 af[4], bfr[4];
#pragma unroll
      for (int mf = 0; mf < 4; mf++) {
        int row = wm * 64 + mf * 16 + (lane & 15);
        af[mf] = *(const short8*)&smA[row * 64 + ((gk ^ (row & 7)) * 8)];
      }
#pragma unroll
      for (int nf = 0; nf < 4; nf++) {
        int nr = wn * 64 + nf * 16 + (lane & 15);
        bfr[nf] = *(const short8*)&smB[nr * 64 + ((gk ^ (nr & 7)) * 8)];
      }
#pragma unroll
      for (int nf = 0; nf < 4; nf++)
#pragma unroll
        for (int mf = 0; mf < 4; mf++)
          acc[mf][nf] = __builtin_amdgcn_mfma_f32_16x16x32_bf16(af[mf], bfr[nf], acc[mf][nf], 0, 0, 0);
    }
    __syncthreads();
  }
#pragma unroll
  for (int mf = 0; mf < 4; mf++)
#pragma unroll
    for (int nf = 0; nf < 4; nf++) {
      int ocr = oc0 + wm * 64 + mf * 16 + ((lane >> 4) << 2);
      int nc = n0 + wn * 64 + nf * 16 + (lane & 15);
#pragma unroll
      for (int j = 0; j < 4; j++)
        storeF(&Yb[(size_t)(ocr + j) * N_ + nc], acc[mf][nf][j]);
    }
}

// ===== gemm_qkvT: xT input; q/v planar stores, k blocks (y=2,3) store transposed =====
__global__ __launch_bounds__(256) void gemm_qkvT(
    const bf16* __restrict__ Wb, const bf16* __restrict__ XT, bf16* __restrict__ Y, int IC) {
  __shared__ short smA[8192];
  __shared__ short smB[8192];
  int tid = threadIdx.x;
  int lane = tid & 63, w = tid >> 6;
  int wm = w >> 1, wn = w & 1;
  int n0 = blockIdx.x * 128, oc0 = blockIdx.y * 128, b = blockIdx.z;
  const bf16* Xb = XT + (size_t)b * N_ * IC;
  bf16* Yb = Y + (size_t)b * 768 * N_;
  f32x4 acc[4][4] = {};

  for (int k0 = 0; k0 < IC; k0 += 64) {
    short8 areg[4], breg[4];
#pragma unroll
    for (int i = 0; i < 4; i++) {
      int q = i * 256 + tid;
      int rowA = q >> 3, gA = q & 7;
      areg[i] = ld8(Wb + (size_t)(oc0 + rowA) * IC + k0 + gA * 8);
      breg[i] = ld8(Xb + (size_t)(n0 + rowA) * IC + k0 + gA * 8);
    }
    __syncthreads();
#pragma unroll
    for (int i = 0; i < 4; i++) {
      int q = i * 256 + tid;
      int rowA = q >> 3, gA = q & 7;
      int so = (gA ^ (rowA & 7)) * 8;
      *(short8*)&smA[rowA * 64 + so] = areg[i];
      *(short8*)&smB[rowA * 64 + so] = breg[i];
    }
    __syncthreads();
#pragma unroll
    for (int ks = 0; ks < 2; ks++) {
      int gk = ks * 4 + (lane >> 4);
      short8 af[4], bfr[4];
#pragma unroll
      for (int mf = 0; mf < 4; mf++) {
        int row = wm * 64 + mf * 16 + (lane & 15);
        af[mf] = *(const short8*)&smA[row * 64 + ((gk ^ (row & 7)) * 8)];
      }
#pragma unroll
      for (int nf = 0; nf < 4; nf++) {
        int nr = wn * 64 + nf * 16 + (lane & 15);
        bfr[nf] = *(const short8*)&smB[nr * 64 + ((gk ^ (nr & 7)) * 8)];
      }
#pragma unroll
      for (int nf = 0; nf < 4; nf++)
#pragma unroll
        for (int mf = 0; mf < 4; mf++)
          acc[mf][nf] = __builtin_amdgcn_mfma_f32_16x16x32_bf16(af[mf], bfr[nf], acc[mf][nf], 0, 0, 0);
    }
    __syncthreads();
  }
  if (oc0 >= 256 && oc0 < 512) {
    bf16* kT = Yb + (size_t)256 * N_;
#pragma unroll
    for (int mf = 0; mf < 4; mf++)
#pragma unroll
      for (int nf = 0; nf < 4; nf++) {
        int ocr = oc0 + wm * 64 + mf * 16 + ((lane >> 4) << 2);
        int nc = n0 + wn * 64 + nf * 16 + (lane & 15);
        int koff = ocr - 256;
        int head = koff >> 5, dc = koff & 31;
        s16x4 ov;
#pragma unroll
        for (int j = 0; j < 4; j++) ov[j] = rawbf(acc[mf][nf][j]);
        *(s16x4*)&kT[((size_t)head * N_ + nc) * 32 + dc] = ov;
      }
  } else {
#pragma unroll
    for (int mf = 0; mf < 4; mf++)
#pragma unroll
      for (int nf = 0; nf < 4; nf++) {
        int ocr = oc0 + wm * 64 + mf * 16 + ((lane >> 4) << 2);
        int nc = n0 + wn * 64 + nf * 16 + (lane & 15);
#pragma unroll
        for (int j = 0; j < 4; j++)
          storeF(&Yb[(size_t)(ocr + j) * N_ + nc], acc[mf][nf][j]);
      }
  }
}

// ===== gemm_qkv (f32 fallback): q/v planar, k transposed =====
template <typename TX>
__global__ __launch_bounds__(256) void gemm_qkv(
    const bf16* __restrict__ Wb, const TX* __restrict__ X, bf16* __restrict__ Y, int IC) {
  __shared__ short smA[8192];
  __shared__ short smB[8192];
  int tid = threadIdx.x;
  int lane = tid & 63, w = tid >> 6;
  int wm = w >> 1, wn = w & 1;
  int n0 = blockIdx.x * 128, oc0 = blockIdx.y * 128, b = blockIdx.z;
  const TX* Xb = X + (size_t)b * IC * N_;
  bf16* Yb = Y + (size_t)b * 768 * N_;
  f32x4 acc[4][4] = {};
  int nB = tid & 127;
  int gB0 = tid >> 7;

  for (int k0 = 0; k0 < IC; k0 += 64) {
    short8 areg[4], breg[4];
#pragma unroll
    for (int i = 0; i < 4; i++) {
      int q = i * 256 + tid;
      int rowA = q >> 3, gA = q & 7;
      areg[i] = ld8(Wb + (size_t)(oc0 + rowA) * IC + k0 + gA * 8);
      int gB = i * 2 + gB0;
      const TX* src = Xb + (size_t)(k0 + gB * 8) * N_ + n0 + nB;
      short8 v;
#pragma unroll
      for (int j = 0; j < 8; j++) v[j] = rawbf(src[(size_t)j * N_]);
      breg[i] = v;
    }
    __syncthreads();
#pragma unroll
    for (int i = 0; i < 4; i++) {
      int q = i * 256 + tid;
      int rowA = q >> 3, gA = q & 7;
      *(short8*)&smA[rowA * 64 + ((gA ^ (rowA & 7)) * 8)] = areg[i];
      int gB = i * 2 + gB0;
      *(short8*)&smB[nB * 64 + ((gB ^ (nB & 7)) * 8)] = breg[i];
    }
    __syncthreads();
#pragma unroll
    for (int ks = 0; ks < 2; ks++) {
      int gk = ks * 4 + (lane >> 4);
      short8 af[4], bfr[4];
#pragma unroll
      for (int mf = 0; mf < 4; mf++) {
        int row = wm * 64 + mf * 16 + (lane & 15);
        af[mf] = *(const short8*)&smA[row * 64 + ((gk ^ (row & 7)) * 8)];
      }
#pragma unroll
      for (int nf = 0; nf < 4; nf++) {
        int nr = wn * 64 + nf * 16 + (lane & 15);
        bfr[nf] = *(const short8*)&smB[nr * 64 + ((gk ^ (nr & 7)) * 8)];
      }
#pragma unroll
      for (int nf = 0; nf < 4; nf++)
#pragma unroll
        for (int mf = 0; mf < 4; mf++)
          acc[mf][nf] = __builtin_amdgcn_mfma_f32_16x16x32_bf16(af[mf], bfr[nf], acc[mf][nf], 0, 0, 0);
    }
    __syncthreads();
  }
  if (oc0 >= 256 && oc0 < 512) {
    bf16* kT = Yb + (size_t)256 * N_;
#pragma unroll
    for (int mf = 0; mf < 4; mf++)
#pragma unroll
      for (int nf = 0; nf < 4; nf++) {
        int ocr = oc0 + wm * 64 + mf * 16 + ((lane >> 4) << 2);
        int nc = n0 + wn * 64 + nf * 16 + (lane & 15);
        int koff = ocr - 256;
        int head = koff >> 5, dc = koff & 31;
        s16x4 ov;
#pragma unroll
        for (int j = 0; j < 4; j++) ov[j] = rawbf(acc[mf][nf][j]);
        *(s16x4*)&kT[((size_t)head * N_ + nc) * 32 + dc] = ov;
      }
  } else {
#pragma unroll
    for (int mf = 0; mf < 4; mf++)
#pragma unroll
      for (int nf = 0; nf < 4; nf++) {
        int ocr = oc0 + wm * 64 + mf * 16 + ((lane >> 4) << 2);
        int nc = n0 + wn * 64 + nf * 16 + (lane & 15);
#pragma unroll
        for (int j = 0; j < 4; j++)
          storeF(&Yb[(size_t)(ocr + j) * N_ + nc], acc[mf][nf][j]);
      }
  }
}

// ===== gemm_mfma_sc: B[c][n] scaled by svec[c]*samap[n] on load =====
__global__ __launch_bounds__(256) void gemm_mfma_sc(
    const bf16* __restrict__ Wb, const bf16* __restrict__ X, bf16* __restrict__ Y, int IC,
    const float* __restrict__ svec, const float* __restrict__ samap) {
  __shared__ short smA[8192];
  __shared__ short smB[8192];
  int tid = threadIdx.x;
  int lane = tid & 63, w = tid >> 6;
  int wm = w >> 1, wn = w & 1;
  int n0 = blockIdx.x * 128, oc0 = blockIdx.y * 128, b = blockIdx.z;
  const bf16* Xb = X + (size_t)b * IC * N_;
  bf16* Yb = Y + (size_t)b * (gridDim.y * 128) * N_;
  f32x4 acc[4][4] = {};
  int nB = tid & 127;
  int gB0 = tid >> 7;
  const float* sv = svec + b * 512;
  float sm = samap[b * N_ + n0 + nB];

  for (int k0 = 0; k0 < IC; k0 += 64) {
    short8 areg[4], breg[4];
#pragma unroll
    for (int i = 0; i < 4; i++) {
      int q = i * 256 + tid;
      int rowA = q >> 3, gA = q & 7;
      areg[i] = ld8(Wb + (size_t)(oc0 + rowA) * IC + k0 + gA * 8);
      int gB = i * 2 + gB0;
      int c0 = k0 + gB * 8;
      const bf16* src = Xb + (size_t)c0 * N_ + n0 + nB;
      short8 v;
#pragma unroll
      for (int j = 0; j < 8; j++)
        v[j] = rawbf(bfs2f(rawbf(src[(size_t)j * N_])) * sv[c0 + j] * sm);
      breg[i] = v;
    }
    __syncthreads();
#pragma unroll
    for (int i = 0; i < 4; i++) {
      int q = i * 256 + tid;
      int rowA = q >> 3, gA = q & 7;
      *(short8*)&smA[rowA * 64 + ((gA ^ (rowA & 7)) * 8)] = areg[i];
      int gB = i * 2 + gB0;
      *(short8*)&smB[nB * 64 + ((gB ^ (nB & 7)) * 8)] = breg[i];
    }
    __syncthreads();
#pragma unroll
    for (int ks = 0; ks < 2; ks++) {
      int gk = ks * 4 + (lane >> 4);
      short8 af[4], bfr[4];
#pragma unroll
      for (int mf = 0; mf < 4; mf++) {
        int row = wm * 64 + mf * 16 + (lane & 15);
        af[mf] = *(const short8*)&smA[row * 64 + ((gk ^ (row & 7)) * 8)];
      }
#pragma unroll
      for (int nf = 0; nf < 4; nf++) {
        int nr = wn * 64 + nf * 16 + (lane & 15);
        bfr[nf] = *(const short8*)&smB[nr * 64 + ((gk ^ (nr & 7)) * 8)];
      }
#pragma unroll
      for (int nf = 0; nf < 4; nf++)
#pragma unroll
        for (int mf = 0; mf < 4; mf++)
          acc[mf][nf] = __builtin_amdgcn_mfma_f32_16x16x32_bf16(af[mf], bfr[nf], acc[mf][nf], 0, 0, 0);
    }
    __syncthreads();
  }
#pragma unroll
  for (int mf = 0; mf < 4; mf++)
#pragma unroll
    for (int nf = 0; nf < 4; nf++) {
      int ocr = oc0 + wm * 64 + mf * 16 + ((lane >> 4) << 2);
      int nc = n0 + wn * 64 + nf * 16 + (lane & 15);
#pragma unroll
      for (int j = 0; j < 4; j++)
        storeF(&Yb[(size_t)(ocr + j) * N_ + nc], acc[mf][nf][j]);
    }
}

// ================= weight f32 -> bf16 (scalar, small tensors) =================
__global__ __launch_bounds__(256) void k_cvt(const float* __restrict__ s,
                                             bf16* __restrict__ d, int n) {
  int i = blockIdx.x * 256 + threadIdx.x;
  if (i < n) d[i] = __float2bfloat16(s[i]);
}

// ======== k_cvtT: x[b][c][n] f32 -> xT[b][n][c] bf16 (fused convert + transpose) ========
__global__ __launch_bounds__(256) void k_cvtT(const float* __restrict__ x,
                                              bf16* __restrict__ xT) {
  int ct = blockIdx.x, nt = blockIdx.y, b = blockIdx.z;
  int c0 = ct * 64, n0 = nt * 128;
  __shared__ float t[64][129];
  int tid = threadIdx.x;
  const float* xb_ = x + ((size_t)b * 256 + c0) * N_ + n0;
#pragma unroll
  for (int i = 0; i < 8; i++) {
    int q = i * 256 + tid;
    int r = q >> 5, col4 = q & 31;
    float4 v = *(const float4*)&xb_[(size_t)r * N_ + col4 * 4];
    t[r][col4 * 4 + 0] = v.x; t[r][col4 * 4 + 1] = v.y;
    t[r][col4 * 4 + 2] = v.z; t[r][col4 * 4 + 3] = v.w;
  }
  __syncthreads();
  bf16* dst = xT + ((size_t)b * N_ + n0) * 256 + c0;
#pragma unroll
  for (int i = 0; i < 4; i++) {
    int q = i * 256 + tid;
    int nl = q >> 3, oct = q & 7;
    short8 v;
#pragma unroll
    for (int j = 0; j < 8; j++) v[j] = rawbf(t[oct * 8 + j][nl]);
    *(short8*)&dst[(size_t)nl * 256 + oct * 8] = v;
  }
}

// ======== LP pool: one block per (cc,b), vectorized loads, templated scale ========
template <int S>
__device__ __forceinline__ void lp_body(const bf16* __restrict__ src,
                                        float* __restrict__ poolout,
                                        float (*part)[6], int tid) {
  int row = tid >> 1, xh = (tid & 1) << 6;
  float partial[6] = {0.f, 0.f, 0.f, 0.f, 0.f, 0.f};
  const bf16* rp = src + row * W_ + xh;
#pragma unroll
  for (int o = 0; o < 8; o++) {
    short8 v = ld8(rp + o * 8);
#pragma unroll
    for (int e = 0; e < 8; e++) {
      float f = bfs2f(v[e]);
      int x = xh + o * 8 + e;
#pragma unroll
      for (int j = 0; j < S; j++) {
        int w0 = (j * W_) / S;
        int w1 = ((j + 1) * W_ + S - 1) / S;
        if (x >= w0 && x < w1) partial[j] += f;
      }
    }
  }
#pragma unroll
  for (int j = 0; j < S; j++) part[tid][j] = partial[j];
  __syncthreads();
  if (tid < S * S) {
    int i = tid / S, j = tid % S;
    int h0 = (i * H_) / S, h1 = ((i + 1) * H_ + S - 1) / S;
    int w0 = (j * W_) / S, w1 = ((j + 1) * W_ + S - 1) / S;
    float sum = 0.f;
    for (int r2 = h0; r2 < h1; r2++) sum += part[r2 * 2][j] + part[r2 * 2 + 1][j];
    poolout[tid] = sum / (float)((h1 - h0) * (w1 - w0));
  }
}

__global__ __launch_bounds__(256) void k_lp_pool(const bf16* __restrict__ qkv,
                                                 float* __restrict__ pools) {
  int cc = blockIdx.x, b = blockIdx.y;
  __shared__ float part[256][6];
  int vch = 512 + (cc & 31) * 8 + (cc >> 5);
  const bf16* src = qkv + ((size_t)b * 768 + vch) * N_;
  float* po = pools + ((size_t)b * 256 + cc) * 36;
  int tid = threadIdx.x;
  int g = cc >> 6;   // block-uniform -> barrier in lp_body is safe
  if (g == 0)      lp_body<1>(src, po, part, tid);
  else if (g == 1) lp_body<2>(src, po, part, tid);
  else if (g == 2) lp_body<3>(src, po, part, tid);
  else             lp_body<6>(src, po, part, tid);
}

// ======== HP conv body (register-blocked 4x4, col-pad 4 / row-pad 3) ========
template <int KSZ>
__device__ __forceinline__ void hp_conv4(const float (*patch)[136], const float* wsm,
                                         int rs4, int cg4, float acc[4][4]) {
  constexpr int ROFF = 3 - KSZ / 2;
  constexpr int COFF = 4 - KSZ / 2;
#pragma unroll
  for (int pr = ROFF; pr < ROFF + KSZ + 3; pr++) {
    float val[12];
    const float* row = &patch[rs4 + pr][cg4];
    *(float4*)&val[0] = *(const float4*)&row[0];
    *(float4*)&val[4] = *(const float4*)&row[4];
    *(float4*)&val[8] = *(const float4*)&row[8];
#pragma unroll
    for (int j = 0; j < 4; j++) {
      int u = pr - ROFF - j;
      if (u >= 0 && u < KSZ) {
#pragma unroll
        for (int v = 0; v < KSZ; v++) {
          float wv = wsm[u * KSZ + v];
#pragma unroll
          for (int c = 0; c < 4; c++) acc[j][c] += val[c + v + COFF] * wv;
        }
      }
    }
  }
}

// ======== fused: HP depthwise conv + LP bilinear-up(relu) + df = q*HP+LP ========
__global__ __launch_bounds__(256) void k_dffuse(const bf16* __restrict__ qkv,
    const float* __restrict__ pools,
    const float* __restrict__ f3w, const float* __restrict__ f3b,
    const float* __restrict__ f5w, const float* __restrict__ f5b,
    const float* __restrict__ f7w, const float* __restrict__ f7b,
    bf16* __restrict__ df) {
  int b = blockIdx.z, cc = blockIdx.y, ty0 = blockIdx.x * 32;
  __shared__ float patch[38][136];
  __shared__ float wsm[49];
  int tid = threadIdx.x;
  int vch = 512 + (cc & 31) * 8 + (cc >> 5);   // v in (d,h) channel decomposition
  const bf16* src = qkv + ((size_t)b * 768 + vch) * N_;
  int ksz; const float* wp; float bias;
  if (cc < 64)       { ksz = 3; wp = f3w + cc * 9;          bias = f3b[cc]; }
  else if (cc < 160) { ksz = 5; wp = f5w + (cc - 64) * 25;  bias = f5b[cc - 64]; }
  else               { ksz = 7; wp = f7w + (cc - 160) * 49; bias = f7b[cc - 160]; }
  if (tid < ksz * ksz) wsm[tid] = wp[tid];
  float4 z4 = make_float4(0.f, 0.f, 0.f, 0.f);
  for (int i4 = tid; i4 < 1292; i4 += 256) ((float4*)patch)[i4] = z4;
  __syncthreads();
  for (int slot = tid; slot < 38 * 16; slot += 256) {
    int py = slot >> 4, seg = slot & 15;
    int gy = ty0 - 3 + py;
    if (gy >= 0 && gy < H_)
      st8f(&patch[py][4 + seg * 8], ld8(&src[gy * W_ + seg * 8]));
  }
  __syncthreads();
  int rs4 = (tid >> 5) * 4, cg4 = (tid & 31) * 4;
  float acc[4][4] = {{bias, bias, bias, bias}, {bias, bias, bias, bias},
                     {bias, bias, bias, bias}, {bias, bias, bias, bias}};
  if (cc < 64)       hp_conv4<3>(patch, wsm, rs4, cg4, acc);
  else if (cc < 160) hp_conv4<5>(patch, wsm, rs4, cg4, acc);
  else               hp_conv4<7>(patch, wsm, rs4, cg4, acc);
  const int S[4] = {1, 2, 3, 6};
  int s = S[cc >> 6];
  const float* pl = pools + ((size_t)b * 256 + cc) * 36;
  int qch = (cc & 31) * 8 + (cc >> 5);
  const bf16* qsrc = qkv + ((size_t)b * 768 + qch) * N_;
#pragma unroll
  for (int j = 0; j < 4; j++) {
    int y = ty0 + rs4 + j;
    float fy = (y + 0.5f) * s * (1.0f / 128.f) - 0.5f;
    int i0r = (int)floorf(fy); float tyf = fy - i0r;
    int i1 = min(max(i0r + 1, 0), s - 1);
    int i0 = min(max(i0r, 0), s - 1);
    s16x4 qv = *(const s16x4*)&qsrc[y * W_ + cg4];
    s16x4 ov;
#pragma unroll
    for (int c = 0; c < 4; c++) {
      int x = cg4 + c;
      float fx = (x + 0.5f) * s * (1.0f / 128.f) - 0.5f;
      int j0r = (int)floorf(fx); float txf = fx - j0r;
      int j1 = min(max(j0r + 1, 0), s - 1);
      int j0 = min(max(j0r, 0), s - 1);
      float v00 = pl[i0 * s + j0], v01 = pl[i0 * s + j1];
      float v10 = pl[i1 * s + j0], v11 = pl[i1 * s + j1];
      float lp = (1.f - tyf) * ((1.f - txf) * v00 + txf * v01) +
                 tyf * ((1.f - txf) * v10 + txf * v11);
      lp = fmaxf(lp, 0.f);
      ov[c] = rawbf(bfs2f(qv[c]) * acc[j][c] + lp);
    }
    *(s16x4*)&df[((size_t)b * 256 + cc) * N_ + y * W_ + cg4] = ov;
  }
}

// ======== window attention — MFMA; K from kT, bias in wave-private LDS, df prefetch ====
__global__ __launch_bounds__(256) void k_attn(const bf16* __restrict__ qkv,
    bf16* __restrict__ df, const float* __restrict__ rel) {
  int b = blockIdx.z, head = blockIdx.y, wg = blockIdx.x;
  int wh = wg >> 2, wc4 = wg & 3;
  __shared__ short P[4][4096];
  __shared__ float biasLds[4][228];
  int tid = threadIdx.x, lane = tid & 63, w = tid >> 6;
  int wc = wc4 * 4 + w;
  short* Pw = P[w];
  float* bw = biasLds[w];
  int lr = lane & 15, lo = lane >> 4;
  int nwin = (wh * 8) * W_ + wc * 8;
  for (int i = lane; i < 225; i += 64) bw[i] = rel[i * 8 + head];
  const bf16* qb = qkv + ((size_t)b * 768 + head * 32 + lo * 8) * N_;
  const bf16* kT = qkv + ((size_t)b * 768 + 256) * N_ + (size_t)head * N_ * 32;
  short8 af[4], bf4[4];
#pragma unroll
  for (int mf = 0; mf < 4; mf++) {
    int l = mf * 16 + lr;
    int n = nwin + (l >> 3) * W_ + (l & 7);
#pragma unroll
    for (int j = 0; j < 8; j++) af[mf][j] = rawbf(qb[(size_t)j * N_ + n]);
    bf4[mf] = ld8(&kT[(size_t)n * 32 + lo * 8]);
  }
  const bf16* dbase = df + ((size_t)b * 256 + head * 32) * N_;
  short8 db[2][2];
#pragma unroll
  for (int ks = 0; ks < 2; ks++)
#pragma unroll
    for (int nf = 0; nf < 2; nf++) {
      int dc = nf * 16 + lr;
      int r = ks * 4 + lo;
      db[ks][nf] = ld8(dbase + (size_t)dc * N_ + nwin + r * W_);
    }
  f32x4 acc[4][4] = {};
#pragma unroll
  for (int nf = 0; nf < 4; nf++)
#pragma unroll
    for (int mf = 0; mf < 4; mf++)
      acc[mf][nf] = __builtin_amdgcn_mfma_f32_16x16x32_bf16(af[mf], bf4[nf], acc[mf][nf], 0, 0, 0);
  const float scale = 0.17677669529663687f;
#pragma unroll
  for (int mf = 0; mf < 4; mf++)
#pragma unroll
    for (int j = 0; j < 4; j++) {
      int lrow = mf * 16 + lo * 4 + j;
      int r1 = lrow >> 3, c1 = lrow & 7;
#pragma unroll
      for (int nf = 0; nf < 4; nf++) {
        int m = nf * 16 + lr;
        acc[mf][nf][j] = acc[mf][nf][j] * scale +
                         bw[(r1 - (m >> 3) + 7) * 15 + (c1 - (m & 7) + 7)];
      }
      float mx = fmaxf(fmaxf(acc[mf][0][j], acc[mf][1][j]),
                       fmaxf(acc[mf][2][j], acc[mf][3][j]));
      mx = fmaxf(mx, __shfl_xor(mx, 1));
      mx = fmaxf(mx, __shfl_xor(mx, 2));
      mx = fmaxf(mx, __shfl_xor(mx, 4));
      mx = fmaxf(mx, __shfl_xor(mx, 8));
      float s = 0.f;
#pragma unroll
      for (int nf = 0; nf < 4; nf++) {
        acc[mf][nf][j] = __expf(acc[mf][nf][j] - mx);
        s += acc[mf][nf][j];
      }
      s += __shfl_xor(s, 1); s += __shfl_xor(s, 2);
      s += __shfl_xor(s, 4); s += __shfl_xor(s, 8);
      float inv = 1.0f / s;
#pragma unroll
      for (int nf = 0; nf < 4; nf++) {
        int m = nf * 16 + lr;
        Pw[lrow * 64 + (((m >> 3) ^ (lrow & 7)) * 8) + (m & 7)] = rawbf(acc[mf][nf][j] * inv);
      }
    }
  __syncthreads();
  f32x4 acc2[4][2] = {};
#pragma unroll
  for (int ks = 0; ks < 2; ks++) {
    short8 pa[4];
#pragma unroll
    for (int mf = 0; mf < 4; mf++) {
      int row = mf * 16 + lr;
      pa[mf] = *(const short8*)&Pw[row * 64 + (((ks * 4 + lo) ^ (row & 7)) * 8)];
    }
#pragma unroll
    for (int nf = 0; nf < 2; nf++)
#pragma unroll
      for (int mf = 0; mf < 4; mf++)
        acc2[mf][nf] = __builtin_amdgcn_mfma_f32_16x16x32_bf16(pa[mf], db[ks][nf], acc2[mf][nf], 0, 0, 0);
  }
#pragma unroll
  for (int mf = 0; mf < 4; mf++)
#pragma unroll
    for (int nf = 0; nf < 2; nf++) {
      int ll = mf * 16 + lo * 4;
      int dc = nf * 16 + lr;
      s16x4 ov;
#pragma unroll
      for (int j = 0; j < 4; j++) ov[j] = rawbf(acc2[mf][nf][j]);
      int n = nwin + (ll >> 3) * W_ + (ll & 7);
      *(s16x4*)&df[((size_t)b * 256 + head * 32 + dc) * N_ + n] = ov;
    }
}

// ================= CBAM: per-channel max/mean (short8 vectorized) =================
__global__ __launch_bounds__(256) void k_chstats(const bf16* __restrict__ loc,
    float* __restrict__ mx, float* __restrict__ av) {
  int c = blockIdx.x, b = blockIdx.y;
  const bf16* p = loc + ((size_t)b * 512 + c) * N_;
  int tid = threadIdx.x;
  float m = -1e30f, s = 0.f;
  for (int i = tid * 8; i < N_; i += 2048) {
    short8 v = *(const short8*)&p[i];
#pragma unroll
    for (int j = 0; j < 8; j++) { float f = bfs2f(v[j]); m = fmaxf(m, f); s += f; }
  }
  __shared__ float rm[256], rs[256];
  rm[tid] = m; rs[tid] = s;
  __syncthreads();
  for (int off = 128; off > 0; off >>= 1) {
    if (tid < off) {
      rm[tid] = fmaxf(rm[tid], rm[tid + off]);
      rs[tid] += rs[tid + off];
    }
    __syncthreads();
  }
  if (tid == 0) { mx[b * 512 + c] = rm[0]; av[b * 512 + c] = rs[0] / (float)N_; }
}

// ========== CBAM MLP layer 1 (wide) ==========
__global__ __launch_bounds__(256) void k_mlp1(const float* __restrict__ mx,
    const float* __restrict__ av,
    const float* __restrict__ w1m, const float* __restrict__ b1m,
    const float* __restrict__ w1a, const float* __restrict__ b1a,
    float* __restrict__ hidden) {
  int path = blockIdx.z, b = blockIdx.y, j0 = blockIdx.x * 64;
  const float* stats = (path ? av : mx) + b * 512;
  const float* w1 = path ? w1a : w1m;
  const float* b1 = path ? b1a : b1m;
  int tid = threadIdx.x, lane = tid & 63, wv = tid >> 6;
#pragma unroll
  for (int jj = 0; jj < 16; jj++) {
    int j = j0 + wv * 16 + jj;
    float a = 0.f;
#pragma unroll
    for (int t = 0; t < 8; t++) {
      int i = lane + t * 64;
      a += stats[i] * w1[j * 512 + i];
    }
#pragma unroll
    for (int off = 32; off > 0; off >>= 1) a += __shfl_xor(a, off);
    if (lane == 0) hidden[(path * 4 + b) * 256 + j] = fmaxf(a + b1[j], 0.f);
  }
}

// ========== CBAM MLP layer 2 (wide) ==========
__global__ __launch_bounds__(256) void k_mlp2(const float* __restrict__ hidden,
    const float* __restrict__ w2m, const float* __restrict__ b2m,
    const float* __restrict__ w2a, const float* __restrict__ b2a,
    float* __restrict__ svec) {
  int b = blockIdx.y, o0 = blockIdx.x * 64;
  const float* hm = hidden + b * 256;
  const float* ha = hidden + (4 + b) * 256;
  int tid = threadIdx.x, lane = tid & 63, wv = tid >> 6;
#pragma unroll
  for (int oo = 0; oo < 16; oo++) {
    int o = o0 + wv * 16 + oo;
    float sm = 0.f, sa = 0.f;
#pragma unroll
    for (int t = 0; t < 4; t++) {
      int jj = lane + t * 64;
      sm += hm[jj] * w2m[o * 256 + jj];
      sa += ha[jj] * w2a[o * 256 + jj];
    }
#pragma unroll
    for (int off = 32; off > 0; off >>= 1) {
      sm += __shfl_xor(sm, off);
      sa += __shfl_xor(sa, off);
    }
    if (lane == 0) {
      float wm = 1.f / (1.f + __expf(-(sm + b2m[o])));
      float wa = 1.f / (1.f + __expf(-(sa + b2a[o])));
      svec[b * 512 + o] = 1.f / (1.f + __expf(-(wm + wa)));
    }
  }
}

// ================= spatial-attn input: per-pixel max/mean (2 px/thread) ===========
__global__ __launch_bounds__(256) void k_cat(const bf16* __restrict__ loc,
    const float* __restrict__ svec, float* __restrict__ catmax, float* __restrict__ catmean) {
  int b = blockIdx.y;
  int n2 = (blockIdx.x * 256 + threadIdx.x) * 2;
  const bf16* lb = loc + (size_t)b * 512 * N_;
  const float* sv = svec + b * 512;
  float m0 = -1e30f, m1 = -1e30f, s0 = 0.f, s1 = 0.f;
#pragma unroll 4
  for (int c = 0; c < 512; c++) {
    unsigned u = *(const unsigned*)&lb[(size_t)c * N_ + n2];
    float sc = sv[c];
    float f0 = __builtin_bit_cast(float, u << 16) * sc;
    float f1 = __builtin_bit_cast(float, u & 0xffff0000u) * sc;
    m0 = fmaxf(m0, f0); s0 += f0;
    m1 = fmaxf(m1, f1); s1 += f1;
  }
  catmax[b * N_ + n2] = m0;     catmax[b * N_ + n2 + 1] = m1;
  catmean[b * N_ + n2] = s0 * (1.f / 512.f);
  catmean[b * N_ + n2 + 1] = s1 * (1.f / 512.f);
}

// ================= spatial attention 7x7 conv -> sigmoid =================
__global__ __launch_bounds__(256) void k_sa(const float* __restrict__ catmax,
    const float* __restrict__ catmean, const float* __restrict__ saw,
    const float* __restrict__ sab, float* __restrict__ samap) {
  int b = blockIdx.y;
  int n = blockIdx.x * 256 + threadIdx.x;
  int y = n >> 7, x = n & 127;
  float acc = sab[0];
  for (int u = 0; u < 7; u++) {
    int yy = y + u - 3;
    if (yy < 0 || yy >= H_) continue;
    for (int v = 0; v < 7; v++) {
      int xx = x + v - 3;
      if (xx < 0 || xx >= W_) continue;
      int nn = b * N_ + yy * W_ + xx;
      acc += catmax[nn] * saw[u * 7 + v] + catmean[nn] * saw[49 + u * 7 + v];
    }
  }
  samap[b * N_ + n] = 1.f / (1.f + __expf(-acc));
}

// ======== fused out1 (directional avg pools + local add) -> dw 8x8 + BN ========
// img patch rows gy=ty0-6..ty0+39 (46), out1 LDS rows oy=ty0-3..ty0+35 (39, with
// oy==128 slot holding out1[126] = dw's reflect), dw outputs rows ty0..ty0+31.
// Numerics identical to the old k_out1+k_dw pair (out1 rounded through bf16).
__global__ __launch_bounds__(256) void k_odw(const bf16* __restrict__ img,
    const bf16* __restrict__ locout,
    const float* __restrict__ dww, const float* __restrict__ bng,
    const float* __restrict__ bnb, bf16* __restrict__ dwo) {
  int b = blockIdx.z, c = blockIdx.y, ty0 = blockIdx.x * 32;
  __shared__ float patch[46][136];
  __shared__ float o1buf[39][136];
  __shared__ float wsm[64];
  int tid = threadIdx.x;
  const bf16* p = img + ((size_t)b * 256 + c) * N_;
  const bf16* lb = locout + ((size_t)b * 256 + c) * N_;
  if (tid < 64) wsm[tid] = dww[c * 64 + tid];
  // zero both buffers (46*136 + 39*136 = 11560 floats = 2890 float4)
  float4 z4 = make_float4(0.f, 0.f, 0.f, 0.f);
  for (int i4 = tid; i4 < 1564; i4 += 256) ((float4*)patch)[i4] = z4;
  for (int i4 = tid; i4 < 1326; i4 += 256) ((float4*)o1buf)[i4] = z4;
  __syncthreads();
  // stage img rows (zero outside [0,128], gy==128 -> img[126]); col 132 = col 126 reflect
  for (int slot = tid; slot < 46 * 16; slot += 256) {
    int py = slot >> 4, seg = slot & 15;
    int gy = ty0 - 6 + py;
    if (gy >= 0 && gy <= 128) {
      int yy = (gy == 128) ? 126 : gy;
      st8f(&patch[py][4 + seg * 8], ld8(&p[yy * W_ + seg * 8]));
    }
  }
  if (tid < 46) {
    int gy = ty0 - 6 + tid;
    if (gy >= 0 && gy <= 128) {
      int yy = (gy == 128) ? 126 : gy;
      patch[tid][132] = toF(p[yy * W_ + 126]);
    }
  }
  __syncthreads();
  // compute out1 rows into o1buf (39 rows x 16 col-octets = 624 slots)
  for (int slot = tid; slot < 624; slot += 256) {
    int q = slot >> 4, oct = slot & 15;
    int oy = ty0 - 3 + q;
    int eff = (oy == 128) ? 126 : oy;
    if (eff >= 0 && eff <= 127) {
      // horizontal window: patch row q+3 (gy = oy), cols oct*8 .. oct*8+15
      float val[16];
      const float* hrow = &patch[q + 3][oct * 8];
      *(float4*)&val[0]  = *(const float4*)&hrow[0];
      *(float4*)&val[4]  = *(const float4*)&hrow[4];
      *(float4*)&val[8]  = *(const float4*)&hrow[8];
      *(float4*)&val[12] = *(const float4*)&hrow[12];
      // vertical: rows q..q+7 at cols oct*8+4 .. +11
      float sv[8] = {};
#pragma unroll
      for (int u = 0; u < 8; u++) {
        const float* vrow = &patch[q + u][oct * 8 + 4];
        float4 a = *(const float4*)&vrow[0];
        float4 bb2 = *(const float4*)&vrow[4];
        sv[0] += a.x; sv[1] += a.y; sv[2] += a.z; sv[3] += a.w;
        sv[4] += bb2.x; sv[5] += bb2.y; sv[6] += bb2.z; sv[7] += bb2.w;
      }
      short8 lo8 = ld8(&lb[eff * W_ + oct * 8]);
#pragma unroll
      for (int e = 0; e < 8; e++) {
        float sh = 0.f;
#pragma unroll
        for (int off = 1; off <= 8; off++) sh += val[e + off];
        float v = 0.125f * (sv[e] + sh) + bfs2f(lo8[e]);
        o1buf[q][4 + oct * 8 + e] = bfs2f(rawbf(v));   // keep bf16 rounding (bit-identical)
      }
    }
  }
  __syncthreads();
  if (tid < 39) o1buf[tid][132] = o1buf[tid][130];   // out1 col 126 reflect for dw
  __syncthreads();
  // dw 8x8 + BN (register-blocked 4x4)
  int rs4 = (tid >> 5) * 4, cg4 = (tid & 31) * 4;
  float acc[4][4] = {};
#pragma unroll
  for (int pr = 0; pr < 11; pr++) {
    float val[12];
    const float* row = &o1buf[rs4 + pr][cg4];
    *(float4*)&val[0] = *(const float4*)&row[0];
    *(float4*)&val[4] = *(const float4*)&row[4];
    *(float4*)&val[8] = *(const float4*)&row[8];
#pragma unroll
    for (int j = 0; j < 4; j++) {
      int u = pr - j;
      if (u >= 0 && u < 8) {
#pragma unroll
        for (int v = 0; v < 8; v++) {
          float wv = wsm[u * 8 + v];
#pragma unroll
          for (int cc2 = 0; cc2 < 4; cc2++) acc[j][cc2] += val[cc2 + v + 1] * wv;
        }
      }
    }
  }
  float g = bng[c] * rsqrtf(1.0f + 1e-5f);
  float bb = bnb[c];
#pragma unroll
  for (int j = 0; j < 4; j++) {
    int y = ty0 + rs4 + j;
    s16x4 ov;
#pragma unroll
    for (int cc2 = 0; cc2 < 4; cc2++) ov[cc2] = rawbf(acc[j][cc2] * g + bb);
    *(s16x4*)&dwo[((size_t)b * 256 + c) * N_ + y * W_ + cg4] = ov;
  }
}

// =========================== launcher ===========================
extern "C" void kernel_launch(void* const* d_in, const int* in_sizes, int n_in,
                              void* d_out, int out_size, void* d_ws, size_t ws_size,
                              hipStream_t stream) {
  const float* x        = (const float*)d_in[0];
  const float* qkv_w    = (const float*)d_in[1];
  const float* ld1_w    = (const float*)d_in[2];
  const float* ld2_w    = (const float*)d_in[3];
  const float* camax_w1 = (const float*)d_in[4];
  const float* camax_b1 = (const float*)d_in[5];
  const float* camax_w2 = (const float*)d_in[6];
  const float* camax_b2 = (const float*)d_in[7];
  const float* caavg_w1 = (const float*)d_in[8];
  const float* caavg_b1 = (const float*)d_in[9];
  const float* caavg_w2 = (const float*)d_in[10];
  const float* caavg_b2 = (const float*)d_in[11];
  const float* sa_w     = (const float*)d_in[12];
  const float* sa_b     = (const float*)d_in[13];
  const float* f3_w     = (const float*)d_in[14];
  const float* f3_b     = (const float*)d_in[15];
  const float* f5_w     = (const float*)d_in[16];
  const float* f5_b     = (const float*)d_in[17];
  const float* f7_w     = (const float*)d_in[18];
  const float* f7_b     = (const float*)d_in[19];
  const float* rel_tab  = (const float*)d_in[20];
  const float* dw_w     = (const float*)d_in[21];
  const float* bn_g     = (const float*)d_in[22];
  const float* bn_b     = (const float*)d_in[23];
  const float* pw_w     = (const float*)d_in[24];
  float* out = (float*)d_out;

  // ---- arena (byte offsets), base peak ~130 MiB ----
  char* wsb = (char*)d_ws;
  bf16* qkvb   = (bf16*)(wsb);                    // [4][768][16384] bf16 = 96 MiB (k region holds kT)
  bf16* dfb    = (bf16*)(wsb + 100663296);        // 32 MiB (df -> img in-place)
  bf16* locb   = (bf16*)(wsb);                    // 64 MiB (qkv dead)
  bf16* locout = (bf16*)(wsb + 67108864);         // 32 MiB
  bf16* dwo    = (bf16*)(wsb + 33554432);         // 32 MiB
  float* small = (float*)(wsb + 134217728);
  float* pools   = small;                         // [4][256][36]
  float* mx      = small + 36864;                 // [4][512]
  float* av      = small + 38912;                 // [4][512]
  float* svec    = small + 40960;                 // [4][512]
  float* catmax  = small + 43008;                 // [4][16384]
  float* catmean = small + 108544;                // [4][16384]
  float* samap   = small + 174080;                // [4][16384]
  float* hidden  = catmax;                        // [2][4][256] — dead before k_cat writes
  bf16* wq  = (bf16*)(wsb + 135176192);           // 768*256
  bf16* wl1 = wq  + 196608;                       // 512*256
  bf16* wl2 = wl1 + 131072;                       // 256*512
  bf16* wpw = wl2 + 131072;                       // 256*256
  bf16* xT = (bf16*)(wsb + 136224768);            // [4][16384][256] bf16 = 32 MiB
  bool use_xb = ws_size >= (size_t)170000000;

  dim3 blk(256);
  k_cvt<<<dim3(768), blk, 0, stream>>>(qkv_w, wq, 196608);
  k_cvt<<<dim3(512), blk, 0, stream>>>(ld1_w, wl1, 131072);
  k_cvt<<<dim3(512), blk, 0, stream>>>(ld2_w, wl2, 131072);
  k_cvt<<<dim3(256), blk, 0, stream>>>(pw_w, wpw, 65536);
  if (use_xb) k_cvtT<<<dim3(4, 128, 4), blk, 0, stream>>>(x, xT);

  // attention / filter branch (k written transposed by the qkv GEMM)
  if (use_xb) gemm_qkvT<<<dim3(128, 6, 4), blk, 0, stream>>>(wq, xT, qkvb, 256);
  else        gemm_qkv<float><<<dim3(128, 6, 4), blk, 0, stream>>>(wq, x, qkvb, 256);
  k_lp_pool<<<dim3(256, 4), blk, 0, stream>>>(qkvb, pools);
  k_dffuse<<<dim3(4, 256, 4), blk, 0, stream>>>(qkvb, pools, f3_w, f3_b, f5_w, f5_b,
                                                f7_w, f7_b, dfb);
  k_attn<<<dim3(64, 8, 4), blk, 0, stream>>>(qkvb, dfb, rel_tab);
  // local (CBAM) branch
  if (use_xb) gemm_mfmaT<<<dim3(128, 4, 4), blk, 0, stream>>>(wl1, xT, locb, 256);
  else        gemm_mfma<float, bf16><<<dim3(128, 4, 4), blk, 0, stream>>>(wl1, x, locb, 256);
  k_chstats<<<dim3(512, 4), blk, 0, stream>>>(locb, mx, av);
  k_mlp1<<<dim3(4, 4, 2), blk, 0, stream>>>(mx, av, camax_w1, camax_b1,
                                            caavg_w1, caavg_b1, hidden);
  k_mlp2<<<dim3(8, 4), blk, 0, stream>>>(hidden, camax_w2, camax_b2,
                                         caavg_w2, caavg_b2, svec);
  k_cat<<<dim3(32, 4), blk, 0, stream>>>(locb, svec, catmax, catmean);
  k_sa<<<dim3(64, 4), blk, 0, stream>>>(catmax, catmean, sa_w, sa_b, samap);
  // ld2 GEMM with svec*samap folded into B-staging
  gemm_mfma_sc<<<dim3(128, 2, 4), blk, 0, stream>>>(wl2, locb, locout, 512, svec, samap);
  // merge + projection (out1+dw fused)
  k_odw<<<dim3(4, 256, 4), blk, 0, stream>>>(dfb, locout, dw_w, bn_g, bn_b, dwo);
  gemm_mfma<bf16, float><<<dim3(128, 2, 4), blk, 0, stream>>>(wpw, dwo, out, 256);
}

// Round 19
// 424.945 us; speedup vs baseline: 1.0307x; 1.0307x over previous
//
#include <hip/hip_runtime.h>
#include <hip/hip_bf16.h>
#include <math.h>

#define B_ 4
#define H_ 128
#define W_ 128
#define N_ 16384

using bf16 = __hip_bfloat16;
typedef short short8 __attribute__((ext_vector_type(8)));
typedef short s16x4 __attribute__((ext_vector_type(4)));
typedef float f32x4 __attribute__((ext_vector_type(4)));

__device__ __forceinline__ float toF(float v) { return v; }
__device__ __forceinline__ float toF(bf16 v) { return __bfloat162float(v); }
__device__ __forceinline__ void storeF(float* p, float v) { *p = v; }
__device__ __forceinline__ void storeF(bf16* p, float v) { *p = __float2bfloat16(v); }

__device__ __forceinline__ unsigned short f2bf(float f) {
  unsigned u = __builtin_bit_cast(unsigned, f);
  unsigned r = (u + 0x7FFFu + ((u >> 16) & 1u)) >> 16;
  return (unsigned short)r;
}
__device__ __forceinline__ short rawbf(float v) { return (short)f2bf(v); }
__device__ __forceinline__ short rawbf(bf16 v) { return __builtin_bit_cast(short, v); }
__device__ __forceinline__ float bfs2f(short s) {
  return __builtin_bit_cast(float, ((unsigned)(unsigned short)s) << 16);
}

// load 8 contiguous bf16 as raw shorts
__device__ __forceinline__ short8 ld8(const bf16* p) { return *(const short8*)p; }

// store short8 (8 bf16) into patch row as 2 aligned float4
__device__ __forceinline__ void st8f(float* dst, short8 v) {
  float4 a, b2;
  a.x = bfs2f(v[0]); a.y = bfs2f(v[1]); a.z = bfs2f(v[2]); a.w = bfs2f(v[3]);
  b2.x = bfs2f(v[4]); b2.y = bfs2f(v[5]); b2.z = bfs2f(v[6]); b2.w = bfs2f(v[7]);
  *(float4*)dst = a;
  *(float4*)(dst + 4) = b2;
}

// ===== MFMA GEMM: Y[b][oc][n] = sum_ic W[oc][ic] * X[b][ic][n] (channel-major X) =====
template <typename TX, typename TY>
__global__ __launch_bounds__(256) void gemm_mfma(
    const bf16* __restrict__ Wb, const TX* __restrict__ X, TY* __restrict__ Y, int IC) {
  __shared__ short smA[8192];
  __shared__ short smB[8192];
  int tid = threadIdx.x;
  int lane = tid & 63, w = tid >> 6;
  int wm = w >> 1, wn = w & 1;
  int n0 = blockIdx.x * 128, oc0 = blockIdx.y * 128, b = blockIdx.z;
  const TX* Xb = X + (size_t)b * IC * N_;
  TY* Yb = Y + (size_t)b * (gridDim.y * 128) * N_;
  f32x4 acc[4][4] = {};
  int nB = tid & 127;
  int gB0 = tid >> 7;

  for (int k0 = 0; k0 < IC; k0 += 64) {
    short8 areg[4], breg[4];
#pragma unroll
    for (int i = 0; i < 4; i++) {
      int q = i * 256 + tid;
      int rowA = q >> 3, gA = q & 7;
      areg[i] = ld8(Wb + (size_t)(oc0 + rowA) * IC + k0 + gA * 8);
      int gB = i * 2 + gB0;
      const TX* src = Xb + (size_t)(k0 + gB * 8) * N_ + n0 + nB;
      short8 v;
#pragma unroll
      for (int j = 0; j < 8; j++) v[j] = rawbf(src[(size_t)j * N_]);
      breg[i] = v;
    }
    __syncthreads();
#pragma unroll
    for (int i = 0; i < 4; i++) {
      int q = i * 256 + tid;
      int rowA = q >> 3, gA = q & 7;
      *(short8*)&smA[rowA * 64 + ((gA ^ (rowA & 7)) * 8)] = areg[i];
      int gB = i * 2 + gB0;
      *(short8*)&smB[nB * 64 + ((gB ^ (nB & 7)) * 8)] = breg[i];
    }
    __syncthreads();
#pragma unroll
    for (int ks = 0; ks < 2; ks++) {
      int gk = ks * 4 + (lane >> 4);
      short8 af[4], bfr[4];
#pragma unroll
      for (int mf = 0; mf < 4; mf++) {
        int row = wm * 64 + mf * 16 + (lane & 15);
        af[mf] = *(const short8*)&smA[row * 64 + ((gk ^ (row & 7)) * 8)];
      }
#pragma unroll
      for (int nf = 0; nf < 4; nf++) {
        int nr = wn * 64 + nf * 16 + (lane & 15);
        bfr[nf] = *(const short8*)&smB[nr * 64 + ((gk ^ (nr & 7)) * 8)];
      }
#pragma unroll
      for (int nf = 0; nf < 4; nf++)
#pragma unroll
        for (int mf = 0; mf < 4; mf++)
          acc[mf][nf] = __builtin_amdgcn_mfma_f32_16x16x32_bf16(af[mf], bfr[nf], acc[mf][nf], 0, 0, 0);
    }
    __syncthreads();
  }
#pragma unroll
  for (int mf = 0; mf < 4; mf++)
#pragma unroll
    for (int nf = 0; nf < 4; nf++) {
      int ocr = oc0 + wm * 64 + mf * 16 + ((lane >> 4) << 2);
      int nc = n0 + wn * 64 + nf * 16 + (lane & 15);
#pragma unroll
      for (int j = 0; j < 4; j++)
        storeF(&Yb[(size_t)(ocr + j) * N_ + nc], acc[mf][nf][j]);
    }
}

// ===== gemm_mfmaT: like gemm_mfma but X is n-major (xT[b][n][ic]); vector B staging =====
__global__ __launch_bounds__(256) void gemm_mfmaT(
    const bf16* __restrict__ Wb, const bf16* __restrict__ XT, bf16* __restrict__ Y, int IC) {
  __shared__ short smA[8192];
  __shared__ short smB[8192];
  int tid = threadIdx.x;
  int lane = tid & 63, w = tid >> 6;
  int wm = w >> 1, wn = w & 1;
  int n0 = blockIdx.x * 128, oc0 = blockIdx.y * 128, b = blockIdx.z;
  const bf16* Xb = XT + (size_t)b * N_ * IC;
  bf16* Yb = Y + (size_t)b * (gridDim.y * 128) * N_;
  f32x4 acc[4][4] = {};

  for (int k0 = 0; k0 < IC; k0 += 64) {
    short8 areg[4], breg[4];
#pragma unroll
    for (int i = 0; i < 4; i++) {
      int q = i * 256 + tid;
      int rowA = q >> 3, gA = q & 7;
      areg[i] = ld8(Wb + (size_t)(oc0 + rowA) * IC + k0 + gA * 8);
      breg[i] = ld8(Xb + (size_t)(n0 + rowA) * IC + k0 + gA * 8);
    }
    __syncthreads();
#pragma unroll
    for (int i = 0; i < 4; i++) {
      int q = i * 256 + tid;
      int rowA = q >> 3, gA = q & 7;
      int so = (gA ^ (rowA & 7)) * 8;
      *(short8*)&smA[rowA * 64 + so] = areg[i];
      *(short8*)&smB[rowA * 64 + so] = breg[i];
    }
    __syncthreads();
#pragma unroll
    for (int ks = 0; ks < 2; ks++) {
      int gk = ks * 4 + (lane >> 4);
      short8 af[4], bfr[4];
#pragma unroll
      for (int mf = 0; mf < 4; mf++) {
        int row = wm * 64 + mf * 16 + (lane & 15);
        af[mf] = *(const short8*)&smA[row * 64 + ((gk ^ (row & 7)) * 8)];
      }
#pragma unroll
      for (int nf = 0; nf < 4; nf++) {
        int nr = wn * 64 + nf * 16 + (lane & 15);
        bfr[nf] = *(const short8*)&smB[nr * 64 + ((gk ^ (nr & 7)) * 8)];
      }
#pragma unroll
      for (int nf = 0; nf < 4; nf++)
#pragma unroll
        for (int mf = 0; mf < 4; mf++)
          acc[mf][nf] = __builtin_amdgcn_mfma_f32_16x16x32_bf16(af[mf], bfr[nf], acc[mf][nf], 0, 0, 0);
    }
    __syncthreads();
  }
#pragma unroll
  for (int mf = 0; mf < 4; mf++)
#pragma unroll
    for (int nf = 0; nf < 4; nf++) {
      int ocr = oc0 + wm * 64 + mf * 16 + ((lane >> 4) << 2);
      int nc = n0 + wn * 64 + nf * 16 + (lane & 15);
#pragma unroll
      for (int j = 0; j < 4; j++)
        storeF(&Yb[(size_t)(ocr + j) * N_ + nc], acc[mf][nf][j]);
    }
}

// ===== gemm_qkvT: xT input; q/v planar stores, k blocks (y=2,3) store transposed =====
__global__ __launch_bounds__(256) void gemm_qkvT(
    const bf16* __restrict__ Wb, const bf16* __restrict__ XT, bf16* __restrict__ Y, int IC) {
  __shared__ short smA[8192];
  __shared__ short smB[8192];
  int tid = threadIdx.x;
  int lane = tid & 63, w = tid >> 6;
  int wm = w >> 1, wn = w & 1;
  int n0 = blockIdx.x * 128, oc0 = blockIdx.y * 128, b = blockIdx.z;
  const bf16* Xb = XT + (size_t)b * N_ * IC;
  bf16* Yb = Y + (size_t)b * 768 * N_;
  f32x4 acc[4][4] = {};

  for (int k0 = 0; k0 < IC; k0 += 64) {
    short8 areg[4], breg[4];
#pragma unroll
    for (int i = 0; i < 4; i++) {
      int q = i * 256 + tid;
      int rowA = q >> 3, gA = q & 7;
      areg[i] = ld8(Wb + (size_t)(oc0 + rowA) * IC + k0 + gA * 8);
      breg[i] = ld8(Xb + (size_t)(n0 + rowA) * IC + k0 + gA * 8);
    }
    __syncthreads();
#pragma unroll
    for (int i = 0; i < 4; i++) {
      int q = i * 256 + tid;
      int rowA = q >> 3, gA = q & 7;
      int so = (gA ^ (rowA & 7)) * 8;
      *(short8*)&smA[rowA * 64 + so] = areg[i];
      *(short8*)&smB[rowA * 64 + so] = breg[i];
    }
    __syncthreads();
#pragma unroll
    for (int ks = 0; ks < 2; ks++) {
      int gk = ks * 4 + (lane >> 4);
      short8 af[4], bfr[4];
#pragma unroll
      for (int mf = 0; mf < 4; mf++) {
        int row = wm * 64 + mf * 16 + (lane & 15);
        af[mf] = *(const short8*)&smA[row * 64 + ((gk ^ (row & 7)) * 8)];
      }
#pragma unroll
      for (int nf = 0; nf < 4; nf++) {
        int nr = wn * 64 + nf * 16 + (lane & 15);
        bfr[nf] = *(const short8*)&smB[nr * 64 + ((gk ^ (nr & 7)) * 8)];
      }
#pragma unroll
      for (int nf = 0; nf < 4; nf++)
#pragma unroll
        for (int mf = 0; mf < 4; mf++)
          acc[mf][nf] = __builtin_amdgcn_mfma_f32_16x16x32_bf16(af[mf], bfr[nf], acc[mf][nf], 0, 0, 0);
    }
    __syncthreads();
  }
  if (oc0 >= 256 && oc0 < 512) {
    bf16* kT = Yb + (size_t)256 * N_;
#pragma unroll
    for (int mf = 0; mf < 4; mf++)
#pragma unroll
      for (int nf = 0; nf < 4; nf++) {
        int ocr = oc0 + wm * 64 + mf * 16 + ((lane >> 4) << 2);
        int nc = n0 + wn * 64 + nf * 16 + (lane & 15);
        int koff = ocr - 256;
        int head = koff >> 5, dc = koff & 31;
        s16x4 ov;
#pragma unroll
        for (int j = 0; j < 4; j++) ov[j] = rawbf(acc[mf][nf][j]);
        *(s16x4*)&kT[((size_t)head * N_ + nc) * 32 + dc] = ov;
      }
  } else {
#pragma unroll
    for (int mf = 0; mf < 4; mf++)
#pragma unroll
      for (int nf = 0; nf < 4; nf++) {
        int ocr = oc0 + wm * 64 + mf * 16 + ((lane >> 4) << 2);
        int nc = n0 + wn * 64 + nf * 16 + (lane & 15);
#pragma unroll
        for (int j = 0; j < 4; j++)
          storeF(&Yb[(size_t)(ocr + j) * N_ + nc], acc[mf][nf][j]);
      }
  }
}

// ===== gemm_qkv (f32 fallback): q/v planar, k transposed =====
template <typename TX>
__global__ __launch_bounds__(256) void gemm_qkv(
    const bf16* __restrict__ Wb, const TX* __restrict__ X, bf16* __restrict__ Y, int IC) {
  __shared__ short smA[8192];
  __shared__ short smB[8192];
  int tid = threadIdx.x;
  int lane = tid & 63, w = tid >> 6;
  int wm = w >> 1, wn = w & 1;
  int n0 = blockIdx.x * 128, oc0 = blockIdx.y * 128, b = blockIdx.z;
  const TX* Xb = X + (size_t)b * IC * N_;
  bf16* Yb = Y + (size_t)b * 768 * N_;
  f32x4 acc[4][4] = {};
  int nB = tid & 127;
  int gB0 = tid >> 7;

  for (int k0 = 0; k0 < IC; k0 += 64) {
    short8 areg[4], breg[4];
#pragma unroll
    for (int i = 0; i < 4; i++) {
      int q = i * 256 + tid;
      int rowA = q >> 3, gA = q & 7;
      areg[i] = ld8(Wb + (size_t)(oc0 + rowA) * IC + k0 + gA * 8);
      int gB = i * 2 + gB0;
      const TX* src = Xb + (size_t)(k0 + gB * 8) * N_ + n0 + nB;
      short8 v;
#pragma unroll
      for (int j = 0; j < 8; j++) v[j] = rawbf(src[(size_t)j * N_]);
      breg[i] = v;
    }
    __syncthreads();
#pragma unroll
    for (int i = 0; i < 4; i++) {
      int q = i * 256 + tid;
      int rowA = q >> 3, gA = q & 7;
      *(short8*)&smA[rowA * 64 + ((gA ^ (rowA & 7)) * 8)] = areg[i];
      int gB = i * 2 + gB0;
      *(short8*)&smB[nB * 64 + ((gB ^ (nB & 7)) * 8)] = breg[i];
    }
    __syncthreads();
#pragma unroll
    for (int ks = 0; ks < 2; ks++) {
      int gk = ks * 4 + (lane >> 4);
      short8 af[4], bfr[4];
#pragma unroll
      for (int mf = 0; mf < 4; mf++) {
        int row = wm * 64 + mf * 16 + (lane & 15);
        af[mf] = *(const short8*)&smA[row * 64 + ((gk ^ (row & 7)) * 8)];
      }
#pragma unroll
      for (int nf = 0; nf < 4; nf++) {
        int nr = wn * 64 + nf * 16 + (lane & 15);
        bfr[nf] = *(const short8*)&smB[nr * 64 + ((gk ^ (nr & 7)) * 8)];
      }
#pragma unroll
      for (int nf = 0; nf < 4; nf++)
#pragma unroll
        for (int mf = 0; mf < 4; mf++)
          acc[mf][nf] = __builtin_amdgcn_mfma_f32_16x16x32_bf16(af[mf], bfr[nf], acc[mf][nf], 0, 0, 0);
    }
    __syncthreads();
  }
  if (oc0 >= 256 && oc0 < 512) {
    bf16* kT = Yb + (size_t)256 * N_;
#pragma unroll
    for (int mf = 0; mf < 4; mf++)
#pragma unroll
      for (int nf = 0; nf < 4; nf++) {
        int ocr = oc0 + wm * 64 + mf * 16 + ((lane >> 4) << 2);
        int nc = n0 + wn * 64 + nf * 16 + (lane & 15);
        int koff = ocr - 256;
        int head = koff >> 5, dc = koff & 31;
        s16x4 ov;
#pragma unroll
        for (int j = 0; j < 4; j++) ov[j] = rawbf(acc[mf][nf][j]);
        *(s16x4*)&kT[((size_t)head * N_ + nc) * 32 + dc] = ov;
      }
  } else {
#pragma unroll
    for (int mf = 0; mf < 4; mf++)
#pragma unroll
      for (int nf = 0; nf < 4; nf++) {
        int ocr = oc0 + wm * 64 + mf * 16 + ((lane >> 4) << 2);
        int nc = n0 + wn * 64 + nf * 16 + (lane & 15);
#pragma unroll
        for (int j = 0; j < 4; j++)
          storeF(&Yb[(size_t)(ocr + j) * N_ + nc], acc[mf][nf][j]);
      }
  }
}

// ===== gemm_mfma_sc: B[c][n] scaled by svec[c]*samap[n] on load =====
__global__ __launch_bounds__(256) void gemm_mfma_sc(
    const bf16* __restrict__ Wb, const bf16* __restrict__ X, bf16* __restrict__ Y, int IC,
    const float* __restrict__ svec, const float* __restrict__ samap) {
  __shared__ short smA[8192];
  __shared__ short smB[8192];
  int tid = threadIdx.x;
  int lane = tid & 63, w = tid >> 6;
  int wm = w >> 1, wn = w & 1;
  int n0 = blockIdx.x * 128, oc0 = blockIdx.y * 128, b = blockIdx.z;
  const bf16* Xb = X + (size_t)b * IC * N_;
  bf16* Yb = Y + (size_t)b * (gridDim.y * 128) * N_;
  f32x4 acc[4][4] = {};
  int nB = tid & 127;
  int gB0 = tid >> 7;
  const float* sv = svec + b * 512;
  float sm = samap[b * N_ + n0 + nB];

  for (int k0 = 0; k0 < IC; k0 += 64) {
    short8 areg[4], breg[4];
#pragma unroll
    for (int i = 0; i < 4; i++) {
      int q = i * 256 + tid;
      int rowA = q >> 3, gA = q & 7;
      areg[i] = ld8(Wb + (size_t)(oc0 + rowA) * IC + k0 + gA * 8);
      int gB = i * 2 + gB0;
      int c0 = k0 + gB * 8;
      const bf16* src = Xb + (size_t)c0 * N_ + n0 + nB;
      short8 v;
#pragma unroll
      for (int j = 0; j < 8; j++)
        v[j] = rawbf(bfs2f(rawbf(src[(size_t)j * N_])) * sv[c0 + j] * sm);
      breg[i] = v;
    }
    __syncthreads();
#pragma unroll
    for (int i = 0; i < 4; i++) {
      int q = i * 256 + tid;
      int rowA = q >> 3, gA = q & 7;
      *(short8*)&smA[rowA * 64 + ((gA ^ (rowA & 7)) * 8)] = areg[i];
      int gB = i * 2 + gB0;
      *(short8*)&smB[nB * 64 + ((gB ^ (nB & 7)) * 8)] = breg[i];
    }
    __syncthreads();
#pragma unroll
    for (int ks = 0; ks < 2; ks++) {
      int gk = ks * 4 + (lane >> 4);
      short8 af[4], bfr[4];
#pragma unroll
      for (int mf = 0; mf < 4; mf++) {
        int row = wm * 64 + mf * 16 + (lane & 15);
        af[mf] = *(const short8*)&smA[row * 64 + ((gk ^ (row & 7)) * 8)];
      }
#pragma unroll
      for (int nf = 0; nf < 4; nf++) {
        int nr = wn * 64 + nf * 16 + (lane & 15);
        bfr[nf] = *(const short8*)&smB[nr * 64 + ((gk ^ (nr & 7)) * 8)];
      }
#pragma unroll
      for (int nf = 0; nf < 4; nf++)
#pragma unroll
        for (int mf = 0; mf < 4; mf++)
          acc[mf][nf] = __builtin_amdgcn_mfma_f32_16x16x32_bf16(af[mf], bfr[nf], acc[mf][nf], 0, 0, 0);
    }
    __syncthreads();
  }
#pragma unroll
  for (int mf = 0; mf < 4; mf++)
#pragma unroll
    for (int nf = 0; nf < 4; nf++) {
      int ocr = oc0 + wm * 64 + mf * 16 + ((lane >> 4) << 2);
      int nc = n0 + wn * 64 + nf * 16 + (lane & 15);
#pragma unroll
      for (int j = 0; j < 4; j++)
        storeF(&Yb[(size_t)(ocr + j) * N_ + nc], acc[mf][nf][j]);
    }
}

// ================= weight f32 -> bf16 (scalar, small tensors) =================
__global__ __launch_bounds__(256) void k_cvt(const float* __restrict__ s,
                                             bf16* __restrict__ d, int n) {
  int i = blockIdx.x * 256 + threadIdx.x;
  if (i < n) d[i] = __float2bfloat16(s[i]);
}

// ======== k_cvtT: x[b][c][n] f32 -> xT[b][n][c] bf16 (fused convert + transpose) ========
__global__ __launch_bounds__(256) void k_cvtT(const float* __restrict__ x,
                                              bf16* __restrict__ xT) {
  int ct = blockIdx.x, nt = blockIdx.y, b = blockIdx.z;
  int c0 = ct * 64, n0 = nt * 128;
  __shared__ float t[64][129];
  int tid = threadIdx.x;
  const float* xb_ = x + ((size_t)b * 256 + c0) * N_ + n0;
#pragma unroll
  for (int i = 0; i < 8; i++) {
    int q = i * 256 + tid;
    int r = q >> 5, col4 = q & 31;
    float4 v = *(const float4*)&xb_[(size_t)r * N_ + col4 * 4];
    t[r][col4 * 4 + 0] = v.x; t[r][col4 * 4 + 1] = v.y;
    t[r][col4 * 4 + 2] = v.z; t[r][col4 * 4 + 3] = v.w;
  }
  __syncthreads();
  bf16* dst = xT + ((size_t)b * N_ + n0) * 256 + c0;
#pragma unroll
  for (int i = 0; i < 4; i++) {
    int q = i * 256 + tid;
    int nl = q >> 3, oct = q & 7;
    short8 v;
#pragma unroll
    for (int j = 0; j < 8; j++) v[j] = rawbf(t[oct * 8 + j][nl]);
    *(short8*)&dst[(size_t)nl * 256 + oct * 8] = v;
  }
}

// ======== LP pool: one block per (cc,b), vectorized loads, templated scale ========
template <int S>
__device__ __forceinline__ void lp_body(const bf16* __restrict__ src,
                                        float* __restrict__ poolout,
                                        float (*part)[6], int tid) {
  int row = tid >> 1, xh = (tid & 1) << 6;
  float partial[6] = {0.f, 0.f, 0.f, 0.f, 0.f, 0.f};
  const bf16* rp = src + row * W_ + xh;
#pragma unroll
  for (int o = 0; o < 8; o++) {
    short8 v = ld8(rp + o * 8);
#pragma unroll
    for (int e = 0; e < 8; e++) {
      float f = bfs2f(v[e]);
      int x = xh + o * 8 + e;
#pragma unroll
      for (int j = 0; j < S; j++) {
        int w0 = (j * W_) / S;
        int w1 = ((j + 1) * W_ + S - 1) / S;
        if (x >= w0 && x < w1) partial[j] += f;
      }
    }
  }
#pragma unroll
  for (int j = 0; j < S; j++) part[tid][j] = partial[j];
  __syncthreads();
  if (tid < S * S) {
    int i = tid / S, j = tid % S;
    int h0 = (i * H_) / S, h1 = ((i + 1) * H_ + S - 1) / S;
    int w0 = (j * W_) / S, w1 = ((j + 1) * W_ + S - 1) / S;
    float sum = 0.f;
    for (int r2 = h0; r2 < h1; r2++) sum += part[r2 * 2][j] + part[r2 * 2 + 1][j];
    poolout[tid] = sum / (float)((h1 - h0) * (w1 - w0));
  }
}

__global__ __launch_bounds__(256) void k_lp_pool(const bf16* __restrict__ qkv,
                                                 float* __restrict__ pools) {
  int cc = blockIdx.x, b = blockIdx.y;
  __shared__ float part[256][6];
  int vch = 512 + (cc & 31) * 8 + (cc >> 5);
  const bf16* src = qkv + ((size_t)b * 768 + vch) * N_;
  float* po = pools + ((size_t)b * 256 + cc) * 36;
  int tid = threadIdx.x;
  int g = cc >> 6;   // block-uniform -> barrier in lp_body is safe
  if (g == 0)      lp_body<1>(src, po, part, tid);
  else if (g == 1) lp_body<2>(src, po, part, tid);
  else if (g == 2) lp_body<3>(src, po, part, tid);
  else             lp_body<6>(src, po, part, tid);
}

// ======== HP conv body (register-blocked 4x4, col-pad 4 / row-pad 3) ========
template <int KSZ>
__device__ __forceinline__ void hp_conv4(const float (*patch)[136], const float* wsm,
                                         int rs4, int cg4, float acc[4][4]) {
  constexpr int ROFF = 3 - KSZ / 2;
  constexpr int COFF = 4 - KSZ / 2;
#pragma unroll
  for (int pr = ROFF; pr < ROFF + KSZ + 3; pr++) {
    float val[12];
    const float* row = &patch[rs4 + pr][cg4];
    *(float4*)&val[0] = *(const float4*)&row[0];
    *(float4*)&val[4] = *(const float4*)&row[4];
    *(float4*)&val[8] = *(const float4*)&row[8];
#pragma unroll
    for (int j = 0; j < 4; j++) {
      int u = pr - ROFF - j;
      if (u >= 0 && u < KSZ) {
#pragma unroll
        for (int v = 0; v < KSZ; v++) {
          float wv = wsm[u * KSZ + v];
#pragma unroll
          for (int c = 0; c < 4; c++) acc[j][c] += val[c + v + COFF] * wv;
        }
      }
    }
  }
}

// ======== fused: HP depthwise conv + LP bilinear-up(relu) + df = q*HP+LP ========
__global__ __launch_bounds__(256) void k_dffuse(const bf16* __restrict__ qkv,
    const float* __restrict__ pools,
    const float* __restrict__ f3w, const float* __restrict__ f3b,
    const float* __restrict__ f5w, const float* __restrict__ f5b,
    const float* __restrict__ f7w, const float* __restrict__ f7b,
    bf16* __restrict__ df) {
  int b = blockIdx.z, cc = blockIdx.y, ty0 = blockIdx.x * 32;
  __shared__ float patch[38][136];
  __shared__ float wsm[49];
  int tid = threadIdx.x;
  int vch = 512 + (cc & 31) * 8 + (cc >> 5);   // v in (d,h) channel decomposition
  const bf16* src = qkv + ((size_t)b * 768 + vch) * N_;
  int ksz; const float* wp; float bias;
  if (cc < 64)       { ksz = 3; wp = f3w + cc * 9;          bias = f3b[cc]; }
  else if (cc < 160) { ksz = 5; wp = f5w + (cc - 64) * 25;  bias = f5b[cc - 64]; }
  else               { ksz = 7; wp = f7w + (cc - 160) * 49; bias = f7b[cc - 160]; }
  if (tid < ksz * ksz) wsm[tid] = wp[tid];
  float4 z4 = make_float4(0.f, 0.f, 0.f, 0.f);
  for (int i4 = tid; i4 < 1292; i4 += 256) ((float4*)patch)[i4] = z4;
  __syncthreads();
  for (int slot = tid; slot < 38 * 16; slot += 256) {
    int py = slot >> 4, seg = slot & 15;
    int gy = ty0 - 3 + py;
    if (gy >= 0 && gy < H_)
      st8f(&patch[py][4 + seg * 8], ld8(&src[gy * W_ + seg * 8]));
  }
  __syncthreads();
  int rs4 = (tid >> 5) * 4, cg4 = (tid & 31) * 4;
  float acc[4][4] = {{bias, bias, bias, bias}, {bias, bias, bias, bias},
                     {bias, bias, bias, bias}, {bias, bias, bias, bias}};
  if (cc < 64)       hp_conv4<3>(patch, wsm, rs4, cg4, acc);
  else if (cc < 160) hp_conv4<5>(patch, wsm, rs4, cg4, acc);
  else               hp_conv4<7>(patch, wsm, rs4, cg4, acc);
  const int S[4] = {1, 2, 3, 6};
  int s = S[cc >> 6];
  const float* pl = pools + ((size_t)b * 256 + cc) * 36;
  int qch = (cc & 31) * 8 + (cc >> 5);
  const bf16* qsrc = qkv + ((size_t)b * 768 + qch) * N_;
#pragma unroll
  for (int j = 0; j < 4; j++) {
    int y = ty0 + rs4 + j;
    float fy = (y + 0.5f) * s * (1.0f / 128.f) - 0.5f;
    int i0r = (int)floorf(fy); float tyf = fy - i0r;
    int i1 = min(max(i0r + 1, 0), s - 1);
    int i0 = min(max(i0r, 0), s - 1);
    s16x4 qv = *(const s16x4*)&qsrc[y * W_ + cg4];
    s16x4 ov;
#pragma unroll
    for (int c = 0; c < 4; c++) {
      int x = cg4 + c;
      float fx = (x + 0.5f) * s * (1.0f / 128.f) - 0.5f;
      int j0r = (int)floorf(fx); float txf = fx - j0r;
      int j1 = min(max(j0r + 1, 0), s - 1);
      int j0 = min(max(j0r, 0), s - 1);
      float v00 = pl[i0 * s + j0], v01 = pl[i0 * s + j1];
      float v10 = pl[i1 * s + j0], v11 = pl[i1 * s + j1];
      float lp = (1.f - tyf) * ((1.f - txf) * v00 + txf * v01) +
                 tyf * ((1.f - txf) * v10 + txf * v11);
      lp = fmaxf(lp, 0.f);
      ov[c] = rawbf(bfs2f(qv[c]) * acc[j][c] + lp);
    }
    *(s16x4*)&df[((size_t)b * 256 + cc) * N_ + y * W_ + cg4] = ov;
  }
}

// ======== window attention — MFMA; K from kT, bias in wave-private LDS, df prefetch ====
__global__ __launch_bounds__(256) void k_attn(const bf16* __restrict__ qkv,
    bf16* __restrict__ df, const float* __restrict__ rel) {
  int b = blockIdx.z, head = blockIdx.y, wg = blockIdx.x;
  int wh = wg >> 2, wc4 = wg & 3;
  __shared__ short P[4][4096];
  __shared__ float biasLds[4][228];
  int tid = threadIdx.x, lane = tid & 63, w = tid >> 6;
  int wc = wc4 * 4 + w;
  short* Pw = P[w];
  float* bw = biasLds[w];
  int lr = lane & 15, lo = lane >> 4;
  int nwin = (wh * 8) * W_ + wc * 8;
  for (int i = lane; i < 225; i += 64) bw[i] = rel[i * 8 + head];
  const bf16* qb = qkv + ((size_t)b * 768 + head * 32 + lo * 8) * N_;
  const bf16* kT = qkv + ((size_t)b * 768 + 256) * N_ + (size_t)head * N_ * 32;
  short8 af[4], bf4[4];
#pragma unroll
  for (int mf = 0; mf < 4; mf++) {
    int l = mf * 16 + lr;
    int n = nwin + (l >> 3) * W_ + (l & 7);
#pragma unroll
    for (int j = 0; j < 8; j++) af[mf][j] = rawbf(qb[(size_t)j * N_ + n]);
    bf4[mf] = ld8(&kT[(size_t)n * 32 + lo * 8]);
  }
  const bf16* dbase = df + ((size_t)b * 256 + head * 32) * N_;
  short8 db[2][2];
#pragma unroll
  for (int ks = 0; ks < 2; ks++)
#pragma unroll
    for (int nf = 0; nf < 2; nf++) {
      int dc = nf * 16 + lr;
      int r = ks * 4 + lo;
      db[ks][nf] = ld8(dbase + (size_t)dc * N_ + nwin + r * W_);
    }
  f32x4 acc[4][4] = {};
#pragma unroll
  for (int nf = 0; nf < 4; nf++)
#pragma unroll
    for (int mf = 0; mf < 4; mf++)
      acc[mf][nf] = __builtin_amdgcn_mfma_f32_16x16x32_bf16(af[mf], bf4[nf], acc[mf][nf], 0, 0, 0);
  const float scale = 0.17677669529663687f;
#pragma unroll
  for (int mf = 0; mf < 4; mf++)
#pragma unroll
    for (int j = 0; j < 4; j++) {
      int lrow = mf * 16 + lo * 4 + j;
      int r1 = lrow >> 3, c1 = lrow & 7;
#pragma unroll
      for (int nf = 0; nf < 4; nf++) {
        int m = nf * 16 + lr;
        acc[mf][nf][j] = acc[mf][nf][j] * scale +
                         bw[(r1 - (m >> 3) + 7) * 15 + (c1 - (m & 7) + 7)];
      }
      float mx = fmaxf(fmaxf(acc[mf][0][j], acc[mf][1][j]),
                       fmaxf(acc[mf][2][j], acc[mf][3][j]));
      mx = fmaxf(mx, __shfl_xor(mx, 1));
      mx = fmaxf(mx, __shfl_xor(mx, 2));
      mx = fmaxf(mx, __shfl_xor(mx, 4));
      mx = fmaxf(mx, __shfl_xor(mx, 8));
      float s = 0.f;
#pragma unroll
      for (int nf = 0; nf < 4; nf++) {
        acc[mf][nf][j] = __expf(acc[mf][nf][j] - mx);
        s += acc[mf][nf][j];
      }
      s += __shfl_xor(s, 1); s += __shfl_xor(s, 2);
      s += __shfl_xor(s, 4); s += __shfl_xor(s, 8);
      float inv = 1.0f / s;
#pragma unroll
      for (int nf = 0; nf < 4; nf++) {
        int m = nf * 16 + lr;
        Pw[lrow * 64 + (((m >> 3) ^ (lrow & 7)) * 8) + (m & 7)] = rawbf(acc[mf][nf][j] * inv);
      }
    }
  __syncthreads();
  f32x4 acc2[4][2] = {};
#pragma unroll
  for (int ks = 0; ks < 2; ks++) {
    short8 pa[4];
#pragma unroll
    for (int mf = 0; mf < 4; mf++) {
      int row = mf * 16 + lr;
      pa[mf] = *(const short8*)&Pw[row * 64 + (((ks * 4 + lo) ^ (row & 7)) * 8)];
    }
#pragma unroll
    for (int nf = 0; nf < 2; nf++)
#pragma unroll
      for (int mf = 0; mf < 4; mf++)
        acc2[mf][nf] = __builtin_amdgcn_mfma_f32_16x16x32_bf16(pa[mf], db[ks][nf], acc2[mf][nf], 0, 0, 0);
  }
#pragma unroll
  for (int mf = 0; mf < 4; mf++)
#pragma unroll
    for (int nf = 0; nf < 2; nf++) {
      int ll = mf * 16 + lo * 4;
      int dc = nf * 16 + lr;
      s16x4 ov;
#pragma unroll
      for (int j = 0; j < 4; j++) ov[j] = rawbf(acc2[mf][nf][j]);
      int n = nwin + (ll >> 3) * W_ + (ll & 7);
      *(s16x4*)&df[((size_t)b * 256 + head * 32 + dc) * N_ + n] = ov;
    }
}

// ================= CBAM: per-channel max/mean (short8 vectorized) =================
__global__ __launch_bounds__(256) void k_chstats(const bf16* __restrict__ loc,
    float* __restrict__ mx, float* __restrict__ av) {
  int c = blockIdx.x, b = blockIdx.y;
  const bf16* p = loc + ((size_t)b * 512 + c) * N_;
  int tid = threadIdx.x;
  float m = -1e30f, s = 0.f;
  for (int i = tid * 8; i < N_; i += 2048) {
    short8 v = *(const short8*)&p[i];
#pragma unroll
    for (int j = 0; j < 8; j++) { float f = bfs2f(v[j]); m = fmaxf(m, f); s += f; }
  }
  __shared__ float rm[256], rs[256];
  rm[tid] = m; rs[tid] = s;
  __syncthreads();
  for (int off = 128; off > 0; off >>= 1) {
    if (tid < off) {
      rm[tid] = fmaxf(rm[tid], rm[tid + off]);
      rs[tid] += rs[tid + off];
    }
    __syncthreads();
  }
  if (tid == 0) { mx[b * 512 + c] = rm[0]; av[b * 512 + c] = rs[0] / (float)N_; }
}

// ========== CBAM MLP layer 1 (wide) ==========
__global__ __launch_bounds__(256) void k_mlp1(const float* __restrict__ mx,
    const float* __restrict__ av,
    const float* __restrict__ w1m, const float* __restrict__ b1m,
    const float* __restrict__ w1a, const float* __restrict__ b1a,
    float* __restrict__ hidden) {
  int path = blockIdx.z, b = blockIdx.y, j0 = blockIdx.x * 64;
  const float* stats = (path ? av : mx) + b * 512;
  const float* w1 = path ? w1a : w1m;
  const float* b1 = path ? b1a : b1m;
  int tid = threadIdx.x, lane = tid & 63, wv = tid >> 6;
#pragma unroll
  for (int jj = 0; jj < 16; jj++) {
    int j = j0 + wv * 16 + jj;
    float a = 0.f;
#pragma unroll
    for (int t = 0; t < 8; t++) {
      int i = lane + t * 64;
      a += stats[i] * w1[j * 512 + i];
    }
#pragma unroll
    for (int off = 32; off > 0; off >>= 1) a += __shfl_xor(a, off);
    if (lane == 0) hidden[(path * 4 + b) * 256 + j] = fmaxf(a + b1[j], 0.f);
  }
}

// ========== CBAM MLP layer 2 (wide) ==========
__global__ __launch_bounds__(256) void k_mlp2(const float* __restrict__ hidden,
    const float* __restrict__ w2m, const float* __restrict__ b2m,
    const float* __restrict__ w2a, const float* __restrict__ b2a,
    float* __restrict__ svec) {
  int b = blockIdx.y, o0 = blockIdx.x * 64;
  const float* hm = hidden + b * 256;
  const float* ha = hidden + (4 + b) * 256;
  int tid = threadIdx.x, lane = tid & 63, wv = tid >> 6;
#pragma unroll
  for (int oo = 0; oo < 16; oo++) {
    int o = o0 + wv * 16 + oo;
    float sm = 0.f, sa = 0.f;
#pragma unroll
    for (int t = 0; t < 4; t++) {
      int jj = lane + t * 64;
      sm += hm[jj] * w2m[o * 256 + jj];
      sa += ha[jj] * w2a[o * 256 + jj];
    }
#pragma unroll
    for (int off = 32; off > 0; off >>= 1) {
      sm += __shfl_xor(sm, off);
      sa += __shfl_xor(sa, off);
    }
    if (lane == 0) {
      float wm = 1.f / (1.f + __expf(-(sm + b2m[o])));
      float wa = 1.f / (1.f + __expf(-(sa + b2a[o])));
      svec[b * 512 + o] = 1.f / (1.f + __expf(-(wm + wa)));
    }
  }
}

// ================= spatial-attn input: per-pixel max/mean (2 px/thread) ===========
__global__ __launch_bounds__(256) void k_cat(const bf16* __restrict__ loc,
    const float* __restrict__ svec, float* __restrict__ catmax, float* __restrict__ catmean) {
  int b = blockIdx.y;
  int n2 = (blockIdx.x * 256 + threadIdx.x) * 2;
  const bf16* lb = loc + (size_t)b * 512 * N_;
  const float* sv = svec + b * 512;
  float m0 = -1e30f, m1 = -1e30f, s0 = 0.f, s1 = 0.f;
#pragma unroll 4
  for (int c = 0; c < 512; c++) {
    unsigned u = *(const unsigned*)&lb[(size_t)c * N_ + n2];
    float sc = sv[c];
    float f0 = __builtin_bit_cast(float, u << 16) * sc;
    float f1 = __builtin_bit_cast(float, u & 0xffff0000u) * sc;
    m0 = fmaxf(m0, f0); s0 += f0;
    m1 = fmaxf(m1, f1); s1 += f1;
  }
  catmax[b * N_ + n2] = m0;     catmax[b * N_ + n2 + 1] = m1;
  catmean[b * N_ + n2] = s0 * (1.f / 512.f);
  catmean[b * N_ + n2 + 1] = s1 * (1.f / 512.f);
}

// ================= spatial attention 7x7 conv -> sigmoid =================
__global__ __launch_bounds__(256) void k_sa(const float* __restrict__ catmax,
    const float* __restrict__ catmean, const float* __restrict__ saw,
    const float* __restrict__ sab, float* __restrict__ samap) {
  int b = blockIdx.y;
  int n = blockIdx.x * 256 + threadIdx.x;
  int y = n >> 7, x = n & 127;
  float acc = sab[0];
  for (int u = 0; u < 7; u++) {
    int yy = y + u - 3;
    if (yy < 0 || yy >= H_) continue;
    for (int v = 0; v < 7; v++) {
      int xx = x + v - 3;
      if (xx < 0 || xx >= W_) continue;
      int nn = b * N_ + yy * W_ + xx;
      acc += catmax[nn] * saw[u * 7 + v] + catmean[nn] * saw[49 + u * 7 + v];
    }
  }
  samap[b * N_ + n] = 1.f / (1.f + __expf(-acc));
}

// ======== directional avg pools + local add — register-blocked 4x4, vector staging ======
__global__ __launch_bounds__(256) void k_out1(const bf16* __restrict__ img,
    const bf16* __restrict__ locout, bf16* __restrict__ out1) {
  int b = blockIdx.z, c = blockIdx.y, ty0 = blockIdx.x * 32;
  __shared__ float patch[39][136];
  int tid = threadIdx.x;
  const bf16* p = img + ((size_t)b * 256 + c) * N_;
  float4 z4 = make_float4(0.f, 0.f, 0.f, 0.f);
  for (int i4 = tid; i4 < 1326; i4 += 256) ((float4*)patch)[i4] = z4;
  __syncthreads();
  for (int slot = tid; slot < 39 * 16; slot += 256) {
    int py = slot >> 4, seg = slot & 15;
    int gy = ty0 - 3 + py;
    if (gy >= 0 && gy <= 128) {
      int yy = (gy == 128) ? 126 : gy;
      st8f(&patch[py][4 + seg * 8], ld8(&p[yy * W_ + seg * 8]));
    }
  }
  if (tid < 39) {
    int gy = ty0 - 3 + tid;
    if (gy >= 0 && gy <= 128) {
      int yy = (gy == 128) ? 126 : gy;
      patch[tid][132] = toF(p[yy * W_ + 126]);   // gx==128 reflect
    }
  }
  __syncthreads();
  int rs4 = (tid >> 5) * 4, cg4 = (tid & 31) * 4;
  float accv[4][4] = {};
  float acch[4][4] = {};
#pragma unroll
  for (int pr = 0; pr < 11; pr++) {
    float val[12];
    const float* row = &patch[rs4 + pr][cg4];
    *(float4*)&val[0] = *(const float4*)&row[0];
    *(float4*)&val[4] = *(const float4*)&row[4];
    *(float4*)&val[8] = *(const float4*)&row[8];
#pragma unroll
    for (int j = 0; j < 4; j++) {
      int u = pr - j;
      if (u >= 0 && u < 8) {
#pragma unroll
        for (int cc2 = 0; cc2 < 4; cc2++) accv[j][cc2] += val[cc2 + 4];
        if (u == 3) {
#pragma unroll
          for (int off = 1; off <= 8; off++)
#pragma unroll
            for (int cc2 = 0; cc2 < 4; cc2++) acch[j][cc2] += val[cc2 + off];
        }
      }
    }
  }
#pragma unroll
  for (int j = 0; j < 4; j++) {
    int y = ty0 + rs4 + j;
    size_t o = ((size_t)b * 256 + c) * N_ + y * W_ + cg4;
    s16x4 lo = *(const s16x4*)&locout[o];
    s16x4 ov;
#pragma unroll
    for (int cc2 = 0; cc2 < 4; cc2++)
      ov[cc2] = rawbf(0.125f * (accv[j][cc2] + acch[j][cc2]) + bfs2f(lo[cc2]));
    *(s16x4*)&out1[o] = ov;
  }
}

// ======== depthwise 8x8 + BN — register-blocked 4x4, vector staging ========
__global__ __launch_bounds__(256) void k_dw(const bf16* __restrict__ out1,
    const float* __restrict__ dww, const float* __restrict__ bng,
    const float* __restrict__ bnb, bf16* __restrict__ dwo) {
  int b = blockIdx.z, c = blockIdx.y, ty0 = blockIdx.x * 32;
  __shared__ float patch[39][136];
  __shared__ float wsm[64];
  int tid = threadIdx.x;
  const bf16* p = out1 + ((size_t)b * 256 + c) * N_;
  if (tid < 64) wsm[tid] = dww[c * 64 + tid];
  float4 z4 = make_float4(0.f, 0.f, 0.f, 0.f);
  for (int i4 = tid; i4 < 1326; i4 += 256) ((float4*)patch)[i4] = z4;
  __syncthreads();
  for (int slot = tid; slot < 39 * 16; slot += 256) {
    int py = slot >> 4, seg = slot & 15;
    int gy = ty0 - 3 + py;
    if (gy >= 0 && gy <= 128) {
      int yy = (gy == 128) ? 126 : gy;
      st8f(&patch[py][4 + seg * 8], ld8(&p[yy * W_ + seg * 8]));
    }
  }
  if (tid < 39) {
    int gy = ty0 - 3 + tid;
    if (gy >= 0 && gy <= 128) {
      int yy = (gy == 128) ? 126 : gy;
      patch[tid][132] = toF(p[yy * W_ + 126]);   // gx==128 reflect
    }
  }
  __syncthreads();
  int rs4 = (tid >> 5) * 4, cg4 = (tid & 31) * 4;
  float acc[4][4] = {};
#pragma unroll
  for (int pr = 0; pr < 11; pr++) {
    float val[12];
    const float* row = &patch[rs4 + pr][cg4];
    *(float4*)&val[0] = *(const float4*)&row[0];
    *(float4*)&val[4] = *(const float4*)&row[4];
    *(float4*)&val[8] = *(const float4*)&row[8];
#pragma unroll
    for (int j = 0; j < 4; j++) {
      int u = pr - j;
      if (u >= 0 && u < 8) {
#pragma unroll
        for (int v = 0; v < 8; v++) {
          float wv = wsm[u * 8 + v];
#pragma unroll
          for (int cc2 = 0; cc2 < 4; cc2++) acc[j][cc2] += val[cc2 + v + 1] * wv;
        }
      }
    }
  }
  float g = bng[c] * rsqrtf(1.0f + 1e-5f);
  float bb = bnb[c];
#pragma unroll
  for (int j = 0; j < 4; j++) {
    int y = ty0 + rs4 + j;
    s16x4 ov;
#pragma unroll
    for (int cc2 = 0; cc2 < 4; cc2++) ov[cc2] = rawbf(acc[j][cc2] * g + bb);
    *(s16x4*)&dwo[((size_t)b * 256 + c) * N_ + y * W_ + cg4] = ov;
  }
}

// =========================== launcher ===========================
extern "C" void kernel_launch(void* const* d_in, const int* in_sizes, int n_in,
                              void* d_out, int out_size, void* d_ws, size_t ws_size,
                              hipStream_t stream) {
  const float* x        = (const float*)d_in[0];
  const float* qkv_w    = (const float*)d_in[1];
  const float* ld1_w    = (const float*)d_in[2];
  const float* ld2_w    = (const float*)d_in[3];
  const float* camax_w1 = (const float*)d_in[4];
  const float* camax_b1 = (const float*)d_in[5];
  const float* camax_w2 = (const float*)d_in[6];
  const float* camax_b2 = (const float*)d_in[7];
  const float* caavg_w1 = (const float*)d_in[8];
  const float* caavg_b1 = (const float*)d_in[9];
  const float* caavg_w2 = (const float*)d_in[10];
  const float* caavg_b2 = (const float*)d_in[11];
  const float* sa_w     = (const float*)d_in[12];
  const float* sa_b     = (const float*)d_in[13];
  const float* f3_w     = (const float*)d_in[14];
  const float* f3_b     = (const float*)d_in[15];
  const float* f5_w     = (const float*)d_in[16];
  const float* f5_b     = (const float*)d_in[17];
  const float* f7_w     = (const float*)d_in[18];
  const float* f7_b     = (const float*)d_in[19];
  const float* rel_tab  = (const float*)d_in[20];
  const float* dw_w     = (const float*)d_in[21];
  const float* bn_g     = (const float*)d_in[22];
  const float* bn_b     = (const float*)d_in[23];
  const float* pw_w     = (const float*)d_in[24];
  float* out = (float*)d_out;

  // ---- arena (byte offsets), base peak ~130 MiB ----
  char* wsb = (char*)d_ws;
  bf16* qkvb   = (bf16*)(wsb);                    // [4][768][16384] bf16 = 96 MiB (k region holds kT)
  bf16* dfb    = (bf16*)(wsb + 100663296);        // 32 MiB (df -> img in-place)
  bf16* locb   = (bf16*)(wsb);                    // 64 MiB (qkv dead)
  bf16* locout = (bf16*)(wsb + 67108864);         // 32 MiB
  bf16* out1   = (bf16*)(wsb);                    // 32 MiB (locb dead)
  bf16* dwo    = (bf16*)(wsb + 33554432);         // 32 MiB
  float* small = (float*)(wsb + 134217728);
  float* pools   = small;                         // [4][256][36]
  float* mx      = small + 36864;                 // [4][512]
  float* av      = small + 38912;                 // [4][512]
  float* svec    = small + 40960;                 // [4][512]
  float* catmax  = small + 43008;                 // [4][16384]
  float* catmean = small + 108544;                // [4][16384]
  float* samap   = small + 174080;                // [4][16384]
  float* hidden  = catmax;                        // [2][4][256] — dead before k_cat writes
  bf16* wq  = (bf16*)(wsb + 135176192);           // 768*256
  bf16* wl1 = wq  + 196608;                       // 512*256
  bf16* wl2 = wl1 + 131072;                       // 256*512
  bf16* wpw = wl2 + 131072;                       // 256*256
  bf16* xT = (bf16*)(wsb + 136224768);            // [4][16384][256] bf16 = 32 MiB
  bool use_xb = ws_size >= (size_t)170000000;

  dim3 blk(256);
  k_cvt<<<dim3(768), blk, 0, stream>>>(qkv_w, wq, 196608);
  k_cvt<<<dim3(512), blk, 0, stream>>>(ld1_w, wl1, 131072);
  k_cvt<<<dim3(512), blk, 0, stream>>>(ld2_w, wl2, 131072);
  k_cvt<<<dim3(256), blk, 0, stream>>>(pw_w, wpw, 65536);
  if (use_xb) k_cvtT<<<dim3(4, 128, 4), blk, 0, stream>>>(x, xT);

  // attention / filter branch (k written transposed by the qkv GEMM)
  if (use_xb) gemm_qkvT<<<dim3(128, 6, 4), blk, 0, stream>>>(wq, xT, qkvb, 256);
  else        gemm_qkv<float><<<dim3(128, 6, 4), blk, 0, stream>>>(wq, x, qkvb, 256);
  k_lp_pool<<<dim3(256, 4), blk, 0, stream>>>(qkvb, pools);
  k_dffuse<<<dim3(4, 256, 4), blk, 0, stream>>>(qkvb, pools, f3_w, f3_b, f5_w, f5_b,
                                                f7_w, f7_b, dfb);
  k_attn<<<dim3(64, 8, 4), blk, 0, stream>>>(qkvb, dfb, rel_tab);
  // local (CBAM) branch
  if (use_xb) gemm_mfmaT<<<dim3(128, 4, 4), blk, 0, stream>>>(wl1, xT, locb, 256);
  else        gemm_mfma<float, bf16><<<dim3(128, 4, 4), blk, 0, stream>>>(wl1, x, locb, 256);
  k_chstats<<<dim3(512, 4), blk, 0, stream>>>(locb, mx, av);
  k_mlp1<<<dim3(4, 4, 2), blk, 0, stream>>>(mx, av, camax_w1, camax_b1,
                                            caavg_w1, caavg_b1, hidden);
  k_mlp2<<<dim3(8, 4), blk, 0, stream>>>(hidden, camax_w2, camax_b2,
                                         caavg_w2, caavg_b2, svec);
  k_cat<<<dim3(32, 4), blk, 0, stream>>>(locb, svec, catmax, catmean);
  k_sa<<<dim3(64, 4), blk, 0, stream>>>(catmax, catmean, sa_w, sa_b, samap);
  // ld2 GEMM with svec*samap folded into B-staging
  gemm_mfma_sc<<<dim3(128, 2, 4), blk, 0, stream>>>(wl2, locb, locout, 512, svec, samap);
  // merge + projection
  k_out1<<<dim3(4, 256, 4), blk, 0, stream>>>(dfb, locout, out1);
  k_dw<<<dim3(4, 256, 4), blk, 0, stream>>>(out1, dw_w, bn_g, bn_b, dwo);
  gemm_mfma<bf16, float><<<dim3(128, 2, 4), blk, 0, stream>>>(wpw, dwo, out, 256);
}